// Round 1
// baseline (1436.293 us; speedup 1.0000x reference)
//
#include <hip/hip_runtime.h>

#define NN 100000
#define EE 600000
#define NQ 200000
#define HID 128
#define NL 4
#define BN_EPS 1e-5f

__device__ __forceinline__ float gelu_f(float v) {
    return 0.5f * v * (1.0f + erff(v * 0.70710678118654752f));
}

// ---------------- small utility kernels ----------------

__global__ void k_zero_int(int* __restrict__ p, int n) {
    int i = blockIdx.x * blockDim.x + threadIdx.x;
    if (i < n) p[i] = 0;
}

__global__ void k_zero_f(float* __restrict__ p, int n) {
    int i = blockIdx.x * blockDim.x + threadIdx.x;
    if (i < n) p[i] = 0.0f;
}

// ---------------- CSR build ----------------

__global__ void k_hist(const int* __restrict__ ei, int* __restrict__ cnt) {
    int e = blockIdx.x * blockDim.x + threadIdx.x;
    if (e < EE) atomicAdd(&cnt[ei[EE + e]], 1);
}

// 1024 elems per block, 256 threads x 4
__global__ void k_scan1(const int* __restrict__ cnt, int* __restrict__ rp,
                        int* __restrict__ bsum, int n) {
    __shared__ int sh[256];
    const int tid = threadIdx.x;
    const int base = blockIdx.x * 1024;
    int v[4];
    int s = 0;
    #pragma unroll
    for (int j = 0; j < 4; ++j) {
        int idx = base + tid * 4 + j;
        v[j] = (idx < n) ? cnt[idx] : 0;
        s += v[j];
    }
    sh[tid] = s;
    __syncthreads();
    for (int off = 1; off < 256; off <<= 1) {
        int t = (tid >= off) ? sh[tid - off] : 0;
        __syncthreads();
        sh[tid] += t;
        __syncthreads();
    }
    int run = sh[tid] - s;  // exclusive prefix within block
    #pragma unroll
    for (int j = 0; j < 4; ++j) {
        int idx = base + tid * 4 + j;
        if (idx < n) rp[idx] = run;
        run += v[j];
    }
    if (tid == 255) bsum[blockIdx.x] = sh[255];
}

__global__ void k_scan2(int* __restrict__ bsum, int nb) {
    __shared__ int sh[256];
    const int tid = threadIdx.x;
    int v = (tid < nb) ? bsum[tid] : 0;
    sh[tid] = v;
    __syncthreads();
    for (int off = 1; off < 256; off <<= 1) {
        int t = (tid >= off) ? sh[tid - off] : 0;
        __syncthreads();
        sh[tid] += t;
        __syncthreads();
    }
    if (tid < nb) bsum[tid] = sh[tid] - v;  // exclusive
}

// add block offsets, zero the cursor (reuses cnt), set rp[n]=EE
__global__ void k_scan3(int* __restrict__ rp, const int* __restrict__ bsum,
                        int* __restrict__ cnt, int n) {
    int i = blockIdx.x * blockDim.x + threadIdx.x;
    if (i < n) {
        rp[i] += bsum[i >> 10];
        cnt[i] = 0;
    }
    if (i == 0) rp[n] = EE;
}

__global__ void k_fill(const int* __restrict__ ei, const float* __restrict__ ea,
                       const int* __restrict__ rp, int* __restrict__ cur,
                       int* __restrict__ csrc, float* __restrict__ cea) {
    int e = blockIdx.x * blockDim.x + threadIdx.x;
    if (e < EE) {
        int d = ei[EE + e];
        int p = rp[d] + atomicAdd(&cur[d], 1);
        csrc[p] = ei[e];
        cea[p] = ea[e];
    }
}

// ---------------- per-node aggregation (one wave per node) ----------------

__global__ void k_gather(const float* __restrict__ x, const int* __restrict__ csrc,
                         const float* __restrict__ cea, const int* __restrict__ rp,
                         float* __restrict__ agg) {
    const int lane = threadIdx.x & 63;
    const int wid = (blockIdx.x * blockDim.x + threadIdx.x) >> 6;
    const int nw = (gridDim.x * blockDim.x) >> 6;
    for (int n = wid; n < NN; n += nw) {
        const int s0 = rp[n], s1 = rp[n + 1];
        float a0 = 0.f, a1 = 0.f;
        for (int i = s0; i < s1; ++i) {
            const int s = csrc[i];
            const float w = cea[i];
            const float2 v = *(const float2*)(x + (size_t)s * HID + (lane << 1));
            a0 += v.x * w;
            a1 += v.y * w;
        }
        *(float2*)(agg + (size_t)n * HID + (lane << 1)) = make_float2(a0, a1);
    }
}

// ---------------- fused GraphConv GEMM: h = gelu([agg|x]@[relw;rootw]+b), BN stats ----------------
// buf holds agg on entry, h on exit (in place, block-disjoint rows).

__global__ __launch_bounds__(256, 2) void k_gemm(
    float* buf, const float* __restrict__ xin,
    const float* __restrict__ relw, const float* __restrict__ rootw,
    const float* __restrict__ relb, float* __restrict__ bnacc, int nrows) {
    __shared__ float As[64][256];
    __shared__ float red[256];
    const int tid = threadIdx.x;
    const int rb = blockIdx.x * 64;
    red[tid] = 0.0f;
    for (int idx = tid; idx < 64 * 64; idx += 256) {
        const int row = idx >> 6;
        const int q = idx & 63;
        const int gr = rb + row;
        float4 v = make_float4(0.f, 0.f, 0.f, 0.f);
        if (gr < nrows) {
            const float* src = (q < 32) ? (buf + (size_t)gr * HID + (q << 2))
                                        : (xin + (size_t)gr * HID + ((q - 32) << 2));
            v = *(const float4*)src;
        }
        *(float4*)&As[row][q << 2] = v;
    }
    __syncthreads();

    const int tcg = tid & 31;
    const int tr = tid >> 5;
    const int c0 = tcg << 2;

    float acc[8][4];
    #pragma unroll
    for (int i = 0; i < 8; ++i)
        #pragma unroll
        for (int j = 0; j < 4; ++j) acc[i][j] = 0.f;

    #pragma unroll 2
    for (int k = 0; k < 2 * HID; k += 4) {
        const float* wb = (k < HID) ? (relw + (size_t)k * HID + c0)
                                    : (rootw + (size_t)(k - HID) * HID + c0);
        const float4 w0 = *(const float4*)(wb);
        const float4 w1 = *(const float4*)(wb + HID);
        const float4 w2 = *(const float4*)(wb + 2 * HID);
        const float4 w3 = *(const float4*)(wb + 3 * HID);
        #pragma unroll
        for (int i = 0; i < 8; ++i) {
            const float4 a = *(const float4*)&As[tr + (i << 3)][k];
            acc[i][0] += a.x * w0.x + a.y * w1.x + a.z * w2.x + a.w * w3.x;
            acc[i][1] += a.x * w0.y + a.y * w1.y + a.z * w2.y + a.w * w3.y;
            acc[i][2] += a.x * w0.z + a.y * w1.z + a.z * w2.z + a.w * w3.z;
            acc[i][3] += a.x * w0.w + a.y * w1.w + a.z * w2.w + a.w * w3.w;
        }
    }

    const float4 bv = *(const float4*)(relb + c0);
    float ps[4] = {0.f, 0.f, 0.f, 0.f}, pq[4] = {0.f, 0.f, 0.f, 0.f};
    #pragma unroll
    for (int i = 0; i < 8; ++i) {
        const int gr = rb + tr + (i << 3);
        const float h0 = gelu_f(acc[i][0] + bv.x);
        const float h1 = gelu_f(acc[i][1] + bv.y);
        const float h2 = gelu_f(acc[i][2] + bv.z);
        const float h3 = gelu_f(acc[i][3] + bv.w);
        if (gr < nrows) {
            *(float4*)(buf + (size_t)gr * HID + c0) = make_float4(h0, h1, h2, h3);
            ps[0] += h0; ps[1] += h1; ps[2] += h2; ps[3] += h3;
            pq[0] += h0 * h0; pq[1] += h1 * h1; pq[2] += h2 * h2; pq[3] += h3 * h3;
        }
    }
    #pragma unroll
    for (int j = 0; j < 4; ++j) {
        atomicAdd(&red[c0 + j], ps[j]);
        atomicAdd(&red[128 + c0 + j], pq[j]);
    }
    __syncthreads();
    atomicAdd(&bnacc[tid], red[tid]);
}

__global__ void k_bnfin(const float* __restrict__ bn, const float* __restrict__ g,
                        const float* __restrict__ b, float* __restrict__ sc) {
    int i = threadIdx.x;
    if (i < 128) {
        const float inv_n = 1.0f / (float)NN;
        const float mean = bn[i] * inv_n;
        const float var = bn[128 + i] * inv_n - mean * mean;
        const float s = g[i] * rsqrtf(var + BN_EPS);
        sc[i] = s;
        sc[128 + i] = b[i] - mean * s;
    }
}

__global__ void k_affine(float* __restrict__ h, const float* __restrict__ sc, int n4) {
    int i = blockIdx.x * blockDim.x + threadIdx.x;
    if (i < n4) {
        const int c = i & 31;
        float4 v = ((float4*)h)[i];
        const float4 s = ((const float4*)sc)[c];
        const float4 t = ((const float4*)(sc + 128))[c];
        v.x = v.x * s.x + t.x;
        v.y = v.y * s.y + t.y;
        v.z = v.z * s.z + t.z;
        v.w = v.w * s.w + t.w;
        ((float4*)h)[i] = v;
    }
}

// ---------------- edge MLP: out = sigmoid(gelu([x[a]|x[b]]@w1+b1)@w2+b2) ----------------

__global__ __launch_bounds__(256, 2) void k_mlp(
    const float* __restrict__ xf, const int* __restrict__ eli,
    const float* __restrict__ w1, const float* __restrict__ b1,
    const float* __restrict__ w2, const float* __restrict__ b2,
    float* __restrict__ out, int nq) {
    __shared__ float Es[64][256];
    const int tid = threadIdx.x;
    const int qb = blockIdx.x * 64;
    for (int idx = tid; idx < 64 * 64; idx += 256) {
        const int row = idx >> 6;
        const int q = idx & 63;
        const int gq = qb + row;
        float4 v = make_float4(0.f, 0.f, 0.f, 0.f);
        if (gq < nq) {
            const int node = (q < 32) ? eli[gq] : eli[NQ + gq];
            v = *(const float4*)(xf + (size_t)node * HID + ((q & 31) << 2));
        }
        *(float4*)&Es[row][q << 2] = v;
    }
    __syncthreads();

    const int tcg = tid & 31;
    const int tr = tid >> 5;
    const int c0 = tcg << 2;

    float acc[8][4];
    #pragma unroll
    for (int i = 0; i < 8; ++i)
        #pragma unroll
        for (int j = 0; j < 4; ++j) acc[i][j] = 0.f;

    #pragma unroll 2
    for (int k = 0; k < 256; k += 4) {
        const float* wb = w1 + (size_t)k * HID + c0;
        const float4 w0 = *(const float4*)(wb);
        const float4 wv1 = *(const float4*)(wb + HID);
        const float4 wv2 = *(const float4*)(wb + 2 * HID);
        const float4 wv3 = *(const float4*)(wb + 3 * HID);
        #pragma unroll
        for (int i = 0; i < 8; ++i) {
            const float4 a = *(const float4*)&Es[tr + (i << 3)][k];
            acc[i][0] += a.x * w0.x + a.y * wv1.x + a.z * wv2.x + a.w * wv3.x;
            acc[i][1] += a.x * w0.y + a.y * wv1.y + a.z * wv2.y + a.w * wv3.y;
            acc[i][2] += a.x * w0.z + a.y * wv1.z + a.z * wv2.z + a.w * wv3.z;
            acc[i][3] += a.x * w0.w + a.y * wv1.w + a.z * wv2.w + a.w * wv3.w;
        }
    }

    const float4 b1v = *(const float4*)(b1 + c0);
    const float4 w2v = *(const float4*)(w2 + c0);
    const float bias2 = b2[0];
    #pragma unroll
    for (int i = 0; i < 8; ++i) {
        const float h0 = gelu_f(acc[i][0] + b1v.x);
        const float h1 = gelu_f(acc[i][1] + b1v.y);
        const float h2 = gelu_f(acc[i][2] + b1v.z);
        const float h3 = gelu_f(acc[i][3] + b1v.w);
        float part = h0 * w2v.x + h1 * w2v.y + h2 * w2v.z + h3 * w2v.w;
        #pragma unroll
        for (int off = 16; off >= 1; off >>= 1) part += __shfl_xor(part, off);
        if (tcg == 0) {
            const int gq = qb + tr + (i << 3);
            if (gq < nq) out[gq] = 1.0f / (1.0f + expf(-(part + bias2)));
        }
    }
}

// ---------------- launcher ----------------

extern "C" void kernel_launch(void* const* d_in, const int* in_sizes, int n_in,
                              void* d_out, int out_size, void* d_ws, size_t ws_size,
                              hipStream_t stream) {
    const float* x_in = (const float*)d_in[0];
    const int* ei = (const int*)d_in[1];
    const float* ea = (const float*)d_in[2];
    const int* eli = (const int*)d_in[3];
    const float* rel_w = (const float*)d_in[4];
    const float* rel_b = (const float*)d_in[5];
    const float* root_w = (const float*)d_in[6];
    const float* bn_g = (const float*)d_in[7];
    const float* bn_b = (const float*)d_in[8];
    const float* w1 = (const float*)d_in[9];
    const float* b1 = (const float*)d_in[10];
    const float* w2 = (const float*)d_in[11];
    const float* b2 = (const float*)d_in[12];
    float* out = (float*)d_out;

    char* ws = (char*)d_ws;
    size_t off = 0;
    auto alloc = [&](size_t bytes) -> void* {
        void* p = ws + off;
        off = (off + bytes + 255) & ~(size_t)255;
        return p;
    };
    float* B0 = (float*)alloc(sizeof(float) * (size_t)NN * HID);
    float* B1 = (float*)alloc(sizeof(float) * (size_t)NN * HID);
    int* csrc = (int*)alloc(sizeof(int) * EE);
    float* cea = (float*)alloc(sizeof(float) * EE);
    int* rp = (int*)alloc(sizeof(int) * (NN + 1));
    int* cnt = (int*)alloc(sizeof(int) * NN);
    int* bsum = (int*)alloc(sizeof(int) * 256);
    float* bn = (float*)alloc(sizeof(float) * 256);
    float* bnsc = (float*)alloc(sizeof(float) * 256);
    (void)ws_size;

    const int nb_scan = (NN + 1023) / 1024;  // 98

    // CSR build
    k_zero_int<<<(NN + 255) / 256, 256, 0, stream>>>(cnt, NN);
    k_hist<<<(EE + 255) / 256, 256, 0, stream>>>(ei, cnt);
    k_scan1<<<nb_scan, 256, 0, stream>>>(cnt, rp, bsum, NN);
    k_scan2<<<1, 256, 0, stream>>>(bsum, nb_scan);
    k_scan3<<<(NN + 255) / 256, 256, 0, stream>>>(rp, bsum, cnt, NN);
    k_fill<<<(EE + 255) / 256, 256, 0, stream>>>(ei, ea, rp, cnt, csrc, cea);

    // 4 GraphConv + BN layers; ping-pong: xin -> B
    const float* xcur = x_in;
    float* bufs[2] = {B0, B1};
    for (int l = 0; l < NL; ++l) {
        float* B = bufs[l & 1];
        k_gather<<<2048, 256, 0, stream>>>(xcur, csrc, cea, rp, B);
        k_zero_f<<<1, 256, 0, stream>>>(bn, 256);
        k_gemm<<<(NN + 63) / 64, 256, 0, stream>>>(
            B, xcur, rel_w + (size_t)l * HID * HID, root_w + (size_t)l * HID * HID,
            rel_b + (size_t)l * HID, bn, NN);
        k_bnfin<<<1, 128, 0, stream>>>(bn, bn_g + (size_t)l * HID, bn_b + (size_t)l * HID, bnsc);
        k_affine<<<(NN * 32 + 255) / 256, 256, 0, stream>>>(B, bnsc, NN * 32);
        xcur = B;
    }

    // edge MLP
    k_mlp<<<(NQ + 63) / 64, 256, 0, stream>>>(xcur, eli, w1, b1, w2, b2, out, NQ);
}

// Round 4
// 1334.842 us; speedup vs baseline: 1.0760x; 1.0760x over previous
//
#include <hip/hip_runtime.h>

#define NN 100000
#define EE 600000
#define NQ 200000
#define HID 128
#define NL 4
#define BN_EPS 1e-5f

typedef __attribute__((ext_vector_type(8))) short short8;
typedef __attribute__((ext_vector_type(4))) float f32x4;

__device__ __forceinline__ float gelu_f(float v) {
    return 0.5f * v * (1.0f + erff(v * 0.70710678118654752f));
}
__device__ __forceinline__ unsigned short f2bf(float f) {
    unsigned int x = __float_as_uint(f);
    unsigned int r = (x + 0x7FFFu + ((x >> 16) & 1u)) >> 16;
    return (unsigned short)r;
}
__device__ __forceinline__ float bf2f(unsigned short u) {
    return __uint_as_float(((unsigned int)u) << 16);
}

// ---------------- small utility kernels ----------------

__global__ void k_zero_int(int* __restrict__ p, int n) {
    int i = blockIdx.x * blockDim.x + threadIdx.x;
    if (i < n) p[i] = 0;
}

__global__ void k_cvt(const float* __restrict__ x, unsigned int* __restrict__ o, int n2) {
    int i = blockIdx.x * blockDim.x + threadIdx.x;
    if (i < n2) {
        float2 v = ((const float2*)x)[i];
        o[i] = (unsigned int)f2bf(v.x) | ((unsigned int)f2bf(v.y) << 16);
    }
}

__global__ void k_bninit(float* __restrict__ sc) {
    int i = threadIdx.x;
    sc[i] = (i < 128) ? 1.0f : 0.0f;
}

// ---------------- CSR build (deterministic) ----------------

__global__ void k_hist(const int* __restrict__ ei, int* __restrict__ cnt) {
    int e = blockIdx.x * blockDim.x + threadIdx.x;
    if (e < EE) atomicAdd(&cnt[ei[EE + e]], 1);  // int atomics: commutative, deterministic result
}

__global__ void k_scan1(const int* __restrict__ cnt, int* __restrict__ rp,
                        int* __restrict__ bsum, int n) {
    __shared__ int sh[256];
    const int tid = threadIdx.x;
    const int base = blockIdx.x * 1024;
    int v[4];
    int s = 0;
    #pragma unroll
    for (int j = 0; j < 4; ++j) {
        int idx = base + tid * 4 + j;
        v[j] = (idx < n) ? cnt[idx] : 0;
        s += v[j];
    }
    sh[tid] = s;
    __syncthreads();
    for (int off = 1; off < 256; off <<= 1) {
        int t = (tid >= off) ? sh[tid - off] : 0;
        __syncthreads();
        sh[tid] += t;
        __syncthreads();
    }
    int run = sh[tid] - s;
    #pragma unroll
    for (int j = 0; j < 4; ++j) {
        int idx = base + tid * 4 + j;
        if (idx < n) rp[idx] = run;
        run += v[j];
    }
    if (tid == 255) bsum[blockIdx.x] = sh[255];
}

__global__ void k_scan2(int* __restrict__ bsum, int nb) {
    __shared__ int sh[256];
    const int tid = threadIdx.x;
    int v = (tid < nb) ? bsum[tid] : 0;
    sh[tid] = v;
    __syncthreads();
    for (int off = 1; off < 256; off <<= 1) {
        int t = (tid >= off) ? sh[tid - off] : 0;
        __syncthreads();
        sh[tid] += t;
        __syncthreads();
    }
    if (tid < nb) bsum[tid] = sh[tid] - v;
}

__global__ void k_scan3(int* __restrict__ rp, const int* __restrict__ bsum,
                        int* __restrict__ cnt, int n) {
    int i = blockIdx.x * blockDim.x + threadIdx.x;
    if (i < n) {
        rp[i] += bsum[i >> 10];
        cnt[i] = 0;
    }
    if (i == 0) rp[n] = EE;
}

// slot assignment is atomic-order-dependent; only edge ids are stored here
__global__ void k_fill(const int* __restrict__ ei, const int* __restrict__ rp,
                       int* __restrict__ cur, int* __restrict__ eord) {
    int e = blockIdx.x * blockDim.x + threadIdx.x;
    if (e < EE) {
        int d = ei[EE + e];
        int p = rp[d] + atomicAdd(&cur[d], 1);
        eord[p] = e;
    }
}

// canonicalize: sort each segment by edge id (deterministic regardless of fill order),
// then materialize csrc/cea and wdeg in that fixed order.
__global__ void k_sortfill(const int* __restrict__ ei, const float* __restrict__ ea,
                           const int* __restrict__ rp, int* __restrict__ eord,
                           int* __restrict__ csrc, float* __restrict__ cea,
                           float* __restrict__ wdeg) {
    int n = blockIdx.x * blockDim.x + threadIdx.x;
    if (n >= NN) return;
    const int s0 = rp[n], s1 = rp[n + 1];
    for (int i = s0 + 1; i < s1; ++i) {
        int key = eord[i];
        int j = i - 1;
        while (j >= s0 && eord[j] > key) { eord[j + 1] = eord[j]; --j; }
        eord[j + 1] = key;
    }
    float s = 0.f;
    for (int i = s0; i < s1; ++i) {
        const int e = eord[i];
        csrc[i] = ei[e];
        const float w = ea[e];
        cea[i] = w;
        s += w;
    }
    wdeg[n] = s;
}

// ---------------- per-node aggregation (one wave per node, bf16) ----------------

__global__ void k_gather(const unsigned short* __restrict__ h, const int* __restrict__ csrc,
                         const float* __restrict__ cea, const int* __restrict__ rp,
                         unsigned short* __restrict__ agg) {
    const int lane = threadIdx.x & 63;
    const int wid = (blockIdx.x * blockDim.x + threadIdx.x) >> 6;
    const int nw = (gridDim.x * blockDim.x) >> 6;
    for (int n = wid; n < NN; n += nw) {
        const int s0 = rp[n], s1 = rp[n + 1];
        float a0 = 0.f, a1 = 0.f;
        for (int i = s0; i < s1; ++i) {
            const int s = csrc[i];
            const float w = cea[i];
            const unsigned int v = *(const unsigned int*)(h + (size_t)s * HID + (lane << 1));
            a0 += bf2f((unsigned short)v) * w;
            a1 += bf2f((unsigned short)(v >> 16)) * w;
        }
        *(unsigned int*)(agg + (size_t)n * HID + (lane << 1)) =
            (unsigned int)f2bf(a0) | ((unsigned int)f2bf(a1) << 16);
    }
}

// ---------------- weight prep (BN affine folded into weights) ----------------

__global__ void k_wprep(const float* __restrict__ relw, const float* __restrict__ rootw,
                        const float* __restrict__ relb, const float* __restrict__ sc,
                        unsigned short* __restrict__ Wt, float* __restrict__ bias2,
                        float* __restrict__ brel) {
    const int tid = threadIdx.x;
    const int k = tid;
    const float s = sc[k & 127];
    const float* src = (k < 128) ? (relw + (size_t)k * HID) : (rootw + (size_t)(k - 128) * HID);
    for (int n = 0; n < 128; ++n) {
        Wt[(size_t)n * 256 + k] = f2bf(s * src[n]);
    }
    if (tid < 128) {
        const int n = tid;
        float ba = relb[n], ra = 0.f;
        for (int kk = 0; kk < 128; ++kk) {
            const float t = sc[128 + kk];
            ba += t * rootw[(size_t)kk * HID + n];
            ra += t * relw[(size_t)kk * HID + n];
        }
        bias2[n] = ba;
        brel[n] = ra;
    }
}

__global__ void k_mlpprep(const float* __restrict__ w1, const float* __restrict__ b1,
                          const float* __restrict__ sc, unsigned short* __restrict__ Wtm,
                          float* __restrict__ b1v) {
    const int tid = threadIdx.x;
    const int k = tid;
    const float s = sc[k & 127];
    for (int n = 0; n < 128; ++n) {
        Wtm[(size_t)n * 256 + k] = f2bf(s * w1[(size_t)k * HID + n]);
    }
    if (tid < 128) {
        const int n = tid;
        float ba = b1[n];
        for (int kk = 0; kk < 256; ++kk) {
            ba += sc[128 + (kk & 127)] * w1[(size_t)kk * HID + n];
        }
        b1v[n] = ba;
    }
}

// ---------------- MFMA conv GEMM (deterministic BN partials) ----------------

__global__ __launch_bounds__(512, 4) void k_gemm2(
    const unsigned short* __restrict__ agg, const unsigned short* __restrict__ hprev,
    const unsigned short* __restrict__ Wt, const float* __restrict__ bias2,
    const float* __restrict__ brel, const float* __restrict__ wdeg,
    unsigned short* __restrict__ hnext, float* __restrict__ bnpart, int nrows) {
    __shared__ unsigned short As[128 * 128];
    __shared__ unsigned short Bs[128 * 128];
    __shared__ float psb[8 * 64];
    __shared__ float pqb[8 * 64];
    const int tid = threadIdx.x;
    const int rb = blockIdx.x * 128;

    const int lane = tid & 63;
    const int wid = tid >> 6;
    const int wm = wid >> 1, wn = wid & 1;

    f32x4 acc[2][4];
    #pragma unroll
    for (int mf = 0; mf < 2; ++mf)
        #pragma unroll
        for (int nf = 0; nf < 4; ++nf) acc[mf][nf] = (f32x4){0.f, 0.f, 0.f, 0.f};

    #pragma unroll
    for (int s = 0; s < 2; ++s) {
        if (s) __syncthreads();
        const unsigned short* srcA = s ? hprev : agg;
        #pragma unroll
        for (int i = 0; i < 4; ++i) {
            const int r = i * 32 + (tid >> 4);
            const int p = tid & 15;
            const int gr = min(rb + r, nrows - 1);
            const int gc = p ^ (r & 7);
            const uint4 v = *(const uint4*)(srcA + (size_t)gr * 128 + gc * 8);
            *(uint4*)(As + r * 128 + p * 8) = v;
        }
        #pragma unroll
        for (int i = 0; i < 4; ++i) {
            const int n = i * 32 + (tid >> 4);
            const int p = tid & 15;
            const int gc = s * 16 + (p ^ (n & 7));
            const uint4 v = *(const uint4*)(Wt + (size_t)n * 256 + gc * 8);
            *(uint4*)(Bs + n * 128 + p * 8) = v;
        }
        __syncthreads();
        #pragma unroll
        for (int kk = 0; kk < 4; ++kk) {
            short8 a[2], b[4];
            #pragma unroll
            for (int mf = 0; mf < 2; ++mf) {
                const int r = wm * 32 + mf * 16 + (lane & 15);
                const int p = (kk * 4 + (lane >> 4)) ^ (r & 7);
                a[mf] = *(const short8*)(As + r * 128 + p * 8);
            }
            #pragma unroll
            for (int nf = 0; nf < 4; ++nf) {
                const int n = wn * 64 + nf * 16 + (lane & 15);
                const int p = (kk * 4 + (lane >> 4)) ^ (n & 7);
                b[nf] = *(const short8*)(Bs + n * 128 + p * 8);
            }
            #pragma unroll
            for (int mf = 0; mf < 2; ++mf)
                #pragma unroll
                for (int nf = 0; nf < 4; ++nf)
                    acc[mf][nf] = __builtin_amdgcn_mfma_f32_16x16x32_bf16(
                        a[mf], b[nf], acc[mf][nf], 0, 0, 0);
        }
    }

    // epilogue: bias + wdeg*brel, gelu, store bf16, BN partials (no atomics)
    int colv[4];
    float biasv[4], brelv[4];
    #pragma unroll
    for (int nf = 0; nf < 4; ++nf) {
        colv[nf] = wn * 64 + nf * 16 + (lane & 15);
        biasv[nf] = bias2[colv[nf]];
        brelv[nf] = brel[colv[nf]];
    }
    float ps[4] = {0.f, 0.f, 0.f, 0.f}, pq[4] = {0.f, 0.f, 0.f, 0.f};
    #pragma unroll
    for (int mf = 0; mf < 2; ++mf) {
        #pragma unroll
        for (int reg = 0; reg < 4; ++reg) {
            const int gm = rb + wm * 32 + mf * 16 + (lane >> 4) * 4 + reg;
            const bool valid = gm < nrows;
            const float wd = valid ? wdeg[gm] : 0.f;
            #pragma unroll
            for (int nf = 0; nf < 4; ++nf) {
                const float hv = gelu_f(acc[mf][nf][reg] + biasv[nf] + wd * brelv[nf]);
                if (valid) {
                    hnext[(size_t)gm * 128 + colv[nf]] = f2bf(hv);
                    ps[nf] += hv;
                    pq[nf] += hv * hv;
                }
            }
        }
    }
    #pragma unroll
    for (int nf = 0; nf < 4; ++nf) {
        // fixed-order reduction across the 4 row-subgroups of this wave
        ps[nf] += __shfl_xor(ps[nf], 16); ps[nf] += __shfl_xor(ps[nf], 32);
        pq[nf] += __shfl_xor(pq[nf], 16); pq[nf] += __shfl_xor(pq[nf], 32);
        if ((lane >> 4) == 0) {
            psb[wid * 64 + nf * 16 + (lane & 15)] = ps[nf];
            pqb[wid * 64 + nf * 16 + (lane & 15)] = pq[nf];
        }
    }
    __syncthreads();
    if (tid < 128) {
        const int wnh = tid >> 6;
        const int c64 = tid & 63;
        float s = 0.f, q = 0.f;
        #pragma unroll
        for (int w = 0; w < 4; ++w) {  // fixed order across waves
            s += psb[(w * 2 + wnh) * 64 + c64];
            q += pqb[(w * 2 + wnh) * 64 + c64];
        }
        bnpart[(size_t)blockIdx.x * 256 + tid] = s;
        bnpart[(size_t)blockIdx.x * 256 + 128 + tid] = q;
    }
}

// deterministic fixed-order reduce of per-block BN partials
__global__ void k_bnred(const float* __restrict__ bnpart, int nblk, float* __restrict__ bn) {
    const int t = threadIdx.x;
    float s = 0.f;
    for (int b = 0; b < nblk; ++b) s += bnpart[(size_t)b * 256 + t];
    bn[t] = s;
}

__global__ void k_bnfin(const float* __restrict__ bn, const float* __restrict__ g,
                        const float* __restrict__ b, float* __restrict__ sc) {
    int i = threadIdx.x;
    if (i < 128) {
        const float inv_n = 1.0f / (float)NN;
        const float mean = bn[i] * inv_n;
        const float var = bn[128 + i] * inv_n - mean * mean;
        const float s = g[i] * rsqrtf(var + BN_EPS);
        sc[i] = s;
        sc[128 + i] = b[i] - mean * s;
    }
}

// ---------------- MFMA edge MLP (deterministic row reduce) ----------------

__global__ __launch_bounds__(512, 4) void k_mlp2(
    const unsigned short* __restrict__ xf, const int* __restrict__ eli,
    const unsigned short* __restrict__ Wtm, const float* __restrict__ b1v,
    const float* __restrict__ w2, const float* __restrict__ b2,
    float* __restrict__ out, int nq) {
    __shared__ unsigned short As[128 * 128];
    __shared__ unsigned short Bs[128 * 128];
    __shared__ int sidx[256];
    __shared__ float rowred2[2][128];
    const int tid = threadIdx.x;
    const int qb = blockIdx.x * 128;
    if (tid < 256) {
        const int rr = tid & 127;
        const int q = qb + rr;
        sidx[tid] = (q < nq) ? eli[(tid >> 7) * NQ + q] : 0;
    }
    __syncthreads();

    const int lane = tid & 63;
    const int wid = tid >> 6;
    const int wm = wid >> 1, wn = wid & 1;

    f32x4 acc[2][4];
    #pragma unroll
    for (int mf = 0; mf < 2; ++mf)
        #pragma unroll
        for (int nf = 0; nf < 4; ++nf) acc[mf][nf] = (f32x4){0.f, 0.f, 0.f, 0.f};

    #pragma unroll
    for (int s = 0; s < 2; ++s) {
        if (s) __syncthreads();
        #pragma unroll
        for (int i = 0; i < 4; ++i) {
            const int r = i * 32 + (tid >> 4);
            const int p = tid & 15;
            const int node = sidx[s * 128 + r];
            const int gc = p ^ (r & 7);
            const uint4 v = *(const uint4*)(xf + (size_t)node * 128 + gc * 8);
            *(uint4*)(As + r * 128 + p * 8) = v;
        }
        #pragma unroll
        for (int i = 0; i < 4; ++i) {
            const int n = i * 32 + (tid >> 4);
            const int p = tid & 15;
            const int gc = s * 16 + (p ^ (n & 7));
            const uint4 v = *(const uint4*)(Wtm + (size_t)n * 256 + gc * 8);
            *(uint4*)(Bs + n * 128 + p * 8) = v;
        }
        __syncthreads();
        #pragma unroll
        for (int kk = 0; kk < 4; ++kk) {
            short8 a[2], b[4];
            #pragma unroll
            for (int mf = 0; mf < 2; ++mf) {
                const int r = wm * 32 + mf * 16 + (lane & 15);
                const int p = (kk * 4 + (lane >> 4)) ^ (r & 7);
                a[mf] = *(const short8*)(As + r * 128 + p * 8);
            }
            #pragma unroll
            for (int nf = 0; nf < 4; ++nf) {
                const int n = wn * 64 + nf * 16 + (lane & 15);
                const int p = (kk * 4 + (lane >> 4)) ^ (n & 7);
                b[nf] = *(const short8*)(Bs + n * 128 + p * 8);
            }
            #pragma unroll
            for (int mf = 0; mf < 2; ++mf)
                #pragma unroll
                for (int nf = 0; nf < 4; ++nf)
                    acc[mf][nf] = __builtin_amdgcn_mfma_f32_16x16x32_bf16(
                        a[mf], b[nf], acc[mf][nf], 0, 0, 0);
        }
    }

    int colv[4];
    float w2v[4], b1c[4];
    #pragma unroll
    for (int nf = 0; nf < 4; ++nf) {
        colv[nf] = wn * 64 + nf * 16 + (lane & 15);
        w2v[nf] = w2[colv[nf]];
        b1c[nf] = b1v[colv[nf]];
    }
    #pragma unroll
    for (int mf = 0; mf < 2; ++mf) {
        #pragma unroll
        for (int reg = 0; reg < 4; ++reg) {
            float part = 0.f;
            #pragma unroll
            for (int nf = 0; nf < 4; ++nf)
                part += gelu_f(acc[mf][nf][reg] + b1c[nf]) * w2v[nf];
            part += __shfl_xor(part, 1);
            part += __shfl_xor(part, 2);
            part += __shfl_xor(part, 4);
            part += __shfl_xor(part, 8);
            if ((lane & 15) == 0) {
                const int lr = wm * 32 + mf * 16 + (lane >> 4) * 4 + reg;
                rowred2[wn][lr] = part;  // unique writer per (wn, lr)
            }
        }
    }
    __syncthreads();
    if (tid < 128) {
        const int q = qb + tid;
        if (q < nq)
            out[q] = 1.0f / (1.0f + expf(-(rowred2[0][tid] + rowred2[1][tid] + b2[0])));
    }
}

// ---------------- launcher ----------------

extern "C" void kernel_launch(void* const* d_in, const int* in_sizes, int n_in,
                              void* d_out, int out_size, void* d_ws, size_t ws_size,
                              hipStream_t stream) {
    const float* x_in = (const float*)d_in[0];
    const int* ei = (const int*)d_in[1];
    const float* ea = (const float*)d_in[2];
    const int* eli = (const int*)d_in[3];
    const float* rel_w = (const float*)d_in[4];
    const float* rel_b = (const float*)d_in[5];
    const float* root_w = (const float*)d_in[6];
    const float* bn_g = (const float*)d_in[7];
    const float* bn_b = (const float*)d_in[8];
    const float* w1 = (const float*)d_in[9];
    const float* b1 = (const float*)d_in[10];
    const float* w2 = (const float*)d_in[11];
    const float* b2 = (const float*)d_in[12];
    float* out = (float*)d_out;

    char* ws = (char*)d_ws;
    size_t off = 0;
    auto alloc = [&](size_t bytes) -> void* {
        void* p = ws + off;
        off = (off + bytes + 255) & ~(size_t)255;
        return p;
    };
    const int nblk_gemm = (NN + 127) / 128;  // 782
    unsigned short* hb0 = (unsigned short*)alloc(2ull * NN * HID);
    unsigned short* hb1 = (unsigned short*)alloc(2ull * NN * HID);
    unsigned short* aggb = (unsigned short*)alloc(2ull * NN * HID);
    int* eord = (int*)alloc(sizeof(int) * EE);
    int* csrc = (int*)alloc(sizeof(int) * EE);
    float* cea = (float*)alloc(sizeof(float) * EE);
    int* rp = (int*)alloc(sizeof(int) * (NN + 1));
    int* cnt = (int*)alloc(sizeof(int) * NN);
    int* bsum = (int*)alloc(sizeof(int) * 256);
    float* wdeg = (float*)alloc(sizeof(float) * NN);
    float* bnpart = (float*)alloc(sizeof(float) * (size_t)nblk_gemm * 256);
    float* bn = (float*)alloc(sizeof(float) * 256);
    float* bnsc = (float*)alloc(sizeof(float) * 256);
    unsigned short* Wt = (unsigned short*)alloc(2ull * 128 * 256);
    unsigned short* Wtm = (unsigned short*)alloc(2ull * 128 * 256);
    float* bias2 = (float*)alloc(sizeof(float) * 128);
    float* brel = (float*)alloc(sizeof(float) * 128);
    float* b1v = (float*)alloc(sizeof(float) * 128);
    (void)ws_size;

    const int nb_scan = (NN + 1023) / 1024;

    // input -> bf16
    k_cvt<<<(NN * 64 + 255) / 256, 256, 0, stream>>>(x_in, (unsigned int*)hb0, NN * 64);

    // CSR build (deterministic final arrays)
    k_zero_int<<<(NN + 255) / 256, 256, 0, stream>>>(cnt, NN);
    k_hist<<<(EE + 255) / 256, 256, 0, stream>>>(ei, cnt);
    k_scan1<<<nb_scan, 256, 0, stream>>>(cnt, rp, bsum, NN);
    k_scan2<<<1, 256, 0, stream>>>(bsum, nb_scan);
    k_scan3<<<(NN + 255) / 256, 256, 0, stream>>>(rp, bsum, cnt, NN);
    k_fill<<<(EE + 255) / 256, 256, 0, stream>>>(ei, rp, cnt, eord);
    k_sortfill<<<(NN + 255) / 256, 256, 0, stream>>>(ei, ea, rp, eord, csrc, cea, wdeg);
    k_bninit<<<1, 256, 0, stream>>>(bnsc);

    unsigned short* hcur = hb0;
    unsigned short* bufs[2] = {hb1, hb0};
    for (int l = 0; l < NL; ++l) {
        unsigned short* hnext = bufs[l & 1];
        k_wprep<<<1, 256, 0, stream>>>(rel_w + (size_t)l * HID * HID,
                                       root_w + (size_t)l * HID * HID,
                                       rel_b + (size_t)l * HID, bnsc, Wt, bias2, brel);
        k_gather<<<2048, 256, 0, stream>>>(hcur, csrc, cea, rp, aggb);
        k_gemm2<<<nblk_gemm, 512, 0, stream>>>(aggb, hcur, Wt, bias2, brel, wdeg,
                                               hnext, bnpart, NN);
        k_bnred<<<1, 256, 0, stream>>>(bnpart, nblk_gemm, bn);
        k_bnfin<<<1, 128, 0, stream>>>(bn, bn_g + (size_t)l * HID, bn_b + (size_t)l * HID, bnsc);
        hcur = hnext;
    }

    k_mlpprep<<<1, 256, 0, stream>>>(w1, b1, bnsc, Wtm, b1v);
    k_mlp2<<<(NQ + 127) / 128, 512, 0, stream>>>(hcur, eli, Wtm, b1v, w2, b2, out, NQ);
}

// Round 5
// 584.012 us; speedup vs baseline: 2.4594x; 2.2856x over previous
//
#include <hip/hip_runtime.h>

#define NN 100000
#define EE 600000
#define NQ 200000
#define HID 128
#define NL 4
#define BN_EPS 1e-5f

typedef __attribute__((ext_vector_type(8))) short short8;
typedef __attribute__((ext_vector_type(4))) float f32x4;

__device__ __forceinline__ float gelu_f(float v) {
    return 0.5f * v * (1.0f + erff(v * 0.70710678118654752f));
}
__device__ __forceinline__ unsigned short f2bf(float f) {
    unsigned int x = __float_as_uint(f);
    unsigned int r = (x + 0x7FFFu + ((x >> 16) & 1u)) >> 16;
    return (unsigned short)r;
}
__device__ __forceinline__ float bf2f(unsigned short u) {
    return __uint_as_float(((unsigned int)u) << 16);
}

// ---------------- small utility kernels ----------------

__global__ void k_zero_int(int* __restrict__ p, int n) {
    int i = blockIdx.x * blockDim.x + threadIdx.x;
    if (i < n) p[i] = 0;
}

__global__ void k_cvt(const float* __restrict__ x, unsigned int* __restrict__ o, int n2) {
    int i = blockIdx.x * blockDim.x + threadIdx.x;
    if (i < n2) {
        float2 v = ((const float2*)x)[i];
        o[i] = (unsigned int)f2bf(v.x) | ((unsigned int)f2bf(v.y) << 16);
    }
}

__global__ void k_bninit(float* __restrict__ sc) {
    int i = threadIdx.x;
    sc[i] = (i < 128) ? 1.0f : 0.0f;
}

// ---------------- CSR build (deterministic) ----------------

__global__ void k_hist(const int* __restrict__ ei, int* __restrict__ cnt) {
    int e = blockIdx.x * blockDim.x + threadIdx.x;
    if (e < EE) atomicAdd(&cnt[ei[EE + e]], 1);  // int atomics: deterministic result
}

__global__ void k_scan1(const int* __restrict__ cnt, int* __restrict__ rp,
                        int* __restrict__ bsum, int n) {
    __shared__ int sh[256];
    const int tid = threadIdx.x;
    const int base = blockIdx.x * 1024;
    int v[4];
    int s = 0;
    #pragma unroll
    for (int j = 0; j < 4; ++j) {
        int idx = base + tid * 4 + j;
        v[j] = (idx < n) ? cnt[idx] : 0;
        s += v[j];
    }
    sh[tid] = s;
    __syncthreads();
    for (int off = 1; off < 256; off <<= 1) {
        int t = (tid >= off) ? sh[tid - off] : 0;
        __syncthreads();
        sh[tid] += t;
        __syncthreads();
    }
    int run = sh[tid] - s;
    #pragma unroll
    for (int j = 0; j < 4; ++j) {
        int idx = base + tid * 4 + j;
        if (idx < n) rp[idx] = run;
        run += v[j];
    }
    if (tid == 255) bsum[blockIdx.x] = sh[255];
}

__global__ void k_scan2(int* __restrict__ bsum, int nb) {
    __shared__ int sh[256];
    const int tid = threadIdx.x;
    int v = (tid < nb) ? bsum[tid] : 0;
    sh[tid] = v;
    __syncthreads();
    for (int off = 1; off < 256; off <<= 1) {
        int t = (tid >= off) ? sh[tid - off] : 0;
        __syncthreads();
        sh[tid] += t;
        __syncthreads();
    }
    if (tid < nb) bsum[tid] = sh[tid] - v;
}

__global__ void k_scan3(int* __restrict__ rp, const int* __restrict__ bsum,
                        int* __restrict__ cnt, int n) {
    int i = blockIdx.x * blockDim.x + threadIdx.x;
    if (i < n) {
        rp[i] += bsum[i >> 10];
        cnt[i] = 0;
    }
    if (i == 0) rp[n] = EE;
}

// slot assignment is atomic-order-dependent; only edge ids are stored here
__global__ void k_fill(const int* __restrict__ ei, const int* __restrict__ rp,
                       int* __restrict__ cur, int* __restrict__ eord) {
    int e = blockIdx.x * blockDim.x + threadIdx.x;
    if (e < EE) {
        int d = ei[EE + e];
        int p = rp[d] + atomicAdd(&cur[d], 1);
        eord[p] = e;
    }
}

// canonicalize: sort each segment by edge id, then materialize csrc/cea/wdeg.
__global__ void k_sortfill(const int* __restrict__ ei, const float* __restrict__ ea,
                           const int* __restrict__ rp, int* __restrict__ eord,
                           int* __restrict__ csrc, float* __restrict__ cea,
                           float* __restrict__ wdeg) {
    int n = blockIdx.x * blockDim.x + threadIdx.x;
    if (n >= NN) return;
    const int s0 = rp[n], s1 = rp[n + 1];
    for (int i = s0 + 1; i < s1; ++i) {
        int key = eord[i];
        int j = i - 1;
        while (j >= s0 && eord[j] > key) { eord[j + 1] = eord[j]; --j; }
        eord[j + 1] = key;
    }
    float s = 0.f;
    for (int i = s0; i < s1; ++i) {
        const int e = eord[i];
        csrc[i] = ei[e];
        const float w = ea[e];
        cea[i] = w;
        s += w;
    }
    wdeg[n] = s;
}

// ---------------- per-node aggregation (one wave per node, bf16) ----------------

__global__ void k_gather(const unsigned short* __restrict__ h, const int* __restrict__ csrc,
                         const float* __restrict__ cea, const int* __restrict__ rp,
                         unsigned short* __restrict__ agg) {
    const int lane = threadIdx.x & 63;
    const int wid = (blockIdx.x * blockDim.x + threadIdx.x) >> 6;
    const int nw = (gridDim.x * blockDim.x) >> 6;
    for (int n = wid; n < NN; n += nw) {
        const int s0 = rp[n], s1 = rp[n + 1];
        float a0 = 0.f, a1 = 0.f;
        for (int i = s0; i < s1; ++i) {
            const int s = csrc[i];
            const float w = cea[i];
            const unsigned int v = *(const unsigned int*)(h + (size_t)s * HID + (lane << 1));
            a0 += bf2f((unsigned short)v) * w;
            a1 += bf2f((unsigned short)(v >> 16)) * w;
        }
        *(unsigned int*)(agg + (size_t)n * HID + (lane << 1)) =
            (unsigned int)f2bf(a0) | ((unsigned int)f2bf(a1) << 16);
    }
}

// ---------------- weight prep (parallel, BN affine folded) ----------------
// grid 128 (n), 256 threads (k). Wt[n][k] = s[k&127]*(k<128?relw[k][n]:rootw[k-128][n])
// brel[n] = sum_k t[k]*relw[k][n]; bias2[n] = relb[n] + sum_k t[k]*rootw[k][n]

__global__ void k_wprep(const float* __restrict__ relw, const float* __restrict__ rootw,
                        const float* __restrict__ relb, const float* __restrict__ sc,
                        unsigned short* __restrict__ Wt, float* __restrict__ bias2,
                        float* __restrict__ brel) {
    __shared__ float shb[256];
    const int n = blockIdx.x;
    const int k = threadIdx.x;
    const float s = sc[k & 127];
    const float w = (k < 128) ? relw[(size_t)k * HID + n] : rootw[(size_t)(k - 128) * HID + n];
    Wt[(size_t)n * 256 + k] = f2bf(s * w);
    shb[k] = sc[128 + (k & 127)] * w;
    __syncthreads();
    #pragma unroll
    for (int off = 64; off >= 1; off >>= 1) {
        if (k < off) shb[k] += shb[k + off];
        else if (k >= 128 && k < 128 + off) shb[k] += shb[k + off];
        __syncthreads();
    }
    if (k == 0) brel[n] = shb[0];
    if (k == 128) bias2[n] = relb[n] + shb[128];
}

// grid 128 (n), 256 threads (k). Wtm[n][k] = s[k&127]*w1[k][n];
// b1v[n] = b1[n] + sum_k t[k&127]*w1[k][n]
__global__ void k_mlpprep(const float* __restrict__ w1, const float* __restrict__ b1,
                          const float* __restrict__ sc, unsigned short* __restrict__ Wtm,
                          float* __restrict__ b1v) {
    __shared__ float shb[256];
    const int n = blockIdx.x;
    const int k = threadIdx.x;
    const float w = w1[(size_t)k * HID + n];
    Wtm[(size_t)n * 256 + k] = f2bf(sc[k & 127] * w);
    shb[k] = sc[128 + (k & 127)] * w;
    __syncthreads();
    #pragma unroll
    for (int off = 128; off >= 1; off >>= 1) {
        if (k < off) shb[k] += shb[k + off];
        __syncthreads();
    }
    if (k == 0) b1v[n] = b1[n] + shb[0];
}

// ---------------- MFMA conv GEMM (deterministic BN partials, transposed layout) ----------------

__global__ __launch_bounds__(512, 4) void k_gemm2(
    const unsigned short* __restrict__ agg, const unsigned short* __restrict__ hprev,
    const unsigned short* __restrict__ Wt, const float* __restrict__ bias2,
    const float* __restrict__ brel, const float* __restrict__ wdeg,
    unsigned short* __restrict__ hnext, float* __restrict__ bnpart,
    int nrows, int nblk) {
    __shared__ unsigned short As[128 * 128];
    __shared__ unsigned short Bs[128 * 128];
    __shared__ float psb[8 * 64];
    __shared__ float pqb[8 * 64];
    const int tid = threadIdx.x;
    const int rb = blockIdx.x * 128;

    const int lane = tid & 63;
    const int wid = tid >> 6;
    const int wm = wid >> 1, wn = wid & 1;

    f32x4 acc[2][4];
    #pragma unroll
    for (int mf = 0; mf < 2; ++mf)
        #pragma unroll
        for (int nf = 0; nf < 4; ++nf) acc[mf][nf] = (f32x4){0.f, 0.f, 0.f, 0.f};

    #pragma unroll
    for (int s = 0; s < 2; ++s) {
        if (s) __syncthreads();
        const unsigned short* srcA = s ? hprev : agg;
        #pragma unroll
        for (int i = 0; i < 4; ++i) {
            const int r = i * 32 + (tid >> 4);
            const int p = tid & 15;
            const int gr = min(rb + r, nrows - 1);
            const int gc = p ^ (r & 7);
            const uint4 v = *(const uint4*)(srcA + (size_t)gr * 128 + gc * 8);
            *(uint4*)(As + r * 128 + p * 8) = v;
        }
        #pragma unroll
        for (int i = 0; i < 4; ++i) {
            const int n = i * 32 + (tid >> 4);
            const int p = tid & 15;
            const int gc = s * 16 + (p ^ (n & 7));
            const uint4 v = *(const uint4*)(Wt + (size_t)n * 256 + gc * 8);
            *(uint4*)(Bs + n * 128 + p * 8) = v;
        }
        __syncthreads();
        #pragma unroll
        for (int kk = 0; kk < 4; ++kk) {
            short8 a[2], b[4];
            #pragma unroll
            for (int mf = 0; mf < 2; ++mf) {
                const int r = wm * 32 + mf * 16 + (lane & 15);
                const int p = (kk * 4 + (lane >> 4)) ^ (r & 7);
                a[mf] = *(const short8*)(As + r * 128 + p * 8);
            }
            #pragma unroll
            for (int nf = 0; nf < 4; ++nf) {
                const int n = wn * 64 + nf * 16 + (lane & 15);
                const int p = (kk * 4 + (lane >> 4)) ^ (n & 7);
                b[nf] = *(const short8*)(Bs + n * 128 + p * 8);
            }
            #pragma unroll
            for (int mf = 0; mf < 2; ++mf)
                #pragma unroll
                for (int nf = 0; nf < 4; ++nf)
                    acc[mf][nf] = __builtin_amdgcn_mfma_f32_16x16x32_bf16(
                        a[mf], b[nf], acc[mf][nf], 0, 0, 0);
        }
    }

    // epilogue: bias + wdeg*brel, gelu, store bf16, BN partials (fixed order, no atomics)
    int colv[4];
    float biasv[4], brelv[4];
    #pragma unroll
    for (int nf = 0; nf < 4; ++nf) {
        colv[nf] = wn * 64 + nf * 16 + (lane & 15);
        biasv[nf] = bias2[colv[nf]];
        brelv[nf] = brel[colv[nf]];
    }
    float ps[4] = {0.f, 0.f, 0.f, 0.f}, pq[4] = {0.f, 0.f, 0.f, 0.f};
    #pragma unroll
    for (int mf = 0; mf < 2; ++mf) {
        #pragma unroll
        for (int reg = 0; reg < 4; ++reg) {
            const int gm = rb + wm * 32 + mf * 16 + (lane >> 4) * 4 + reg;
            const bool valid = gm < nrows;
            const float wd = valid ? wdeg[gm] : 0.f;
            #pragma unroll
            for (int nf = 0; nf < 4; ++nf) {
                const float hv = gelu_f(acc[mf][nf][reg] + biasv[nf] + wd * brelv[nf]);
                if (valid) {
                    hnext[(size_t)gm * 128 + colv[nf]] = f2bf(hv);
                    ps[nf] += hv;
                    pq[nf] += hv * hv;
                }
            }
        }
    }
    #pragma unroll
    for (int nf = 0; nf < 4; ++nf) {
        ps[nf] += __shfl_xor(ps[nf], 16); ps[nf] += __shfl_xor(ps[nf], 32);
        pq[nf] += __shfl_xor(pq[nf], 16); pq[nf] += __shfl_xor(pq[nf], 32);
        if ((lane >> 4) == 0) {
            psb[wid * 64 + nf * 16 + (lane & 15)] = ps[nf];
            pqb[wid * 64 + nf * 16 + (lane & 15)] = pq[nf];
        }
    }
    __syncthreads();
    if (tid < 128) {
        const int wnh = tid >> 6;
        const int c64 = tid & 63;
        float s = 0.f, q = 0.f;
        #pragma unroll
        for (int w = 0; w < 4; ++w) {  // fixed order across waves
            s += psb[(w * 2 + wnh) * 64 + c64];
            q += pqb[(w * 2 + wnh) * 64 + c64];
        }
        // transposed layout: [col][block] for coalesced parallel reduce
        bnpart[(size_t)tid * nblk + blockIdx.x] = s;
        bnpart[(size_t)(128 + tid) * nblk + blockIdx.x] = q;
    }
}

// parallel deterministic reduce: one block per column, coalesced reads, fixed-order tree
__global__ void k_bnred(const float* __restrict__ bnpart, int nblk, float* __restrict__ bn) {
    __shared__ float sh[256];
    const int tid = threadIdx.x;
    const int col = blockIdx.x;
    float s = 0.f;
    for (int i = tid; i < nblk; i += 256) s += bnpart[(size_t)col * nblk + i];
    sh[tid] = s;
    __syncthreads();
    #pragma unroll
    for (int off = 128; off >= 1; off >>= 1) {
        if (tid < off) sh[tid] += sh[tid + off];
        __syncthreads();
    }
    if (tid == 0) bn[col] = sh[0];
}

__global__ void k_bnfin(const float* __restrict__ bn, const float* __restrict__ g,
                        const float* __restrict__ b, float* __restrict__ sc) {
    int i = threadIdx.x;
    if (i < 128) {
        const float inv_n = 1.0f / (float)NN;
        const float mean = bn[i] * inv_n;
        const float var = bn[128 + i] * inv_n - mean * mean;
        const float s = g[i] * rsqrtf(var + BN_EPS);
        sc[i] = s;
        sc[128 + i] = b[i] - mean * s;
    }
}

// ---------------- MFMA edge MLP (deterministic row reduce) ----------------

__global__ __launch_bounds__(512, 4) void k_mlp2(
    const unsigned short* __restrict__ xf, const int* __restrict__ eli,
    const unsigned short* __restrict__ Wtm, const float* __restrict__ b1v,
    const float* __restrict__ w2, const float* __restrict__ b2,
    float* __restrict__ out, int nq) {
    __shared__ unsigned short As[128 * 128];
    __shared__ unsigned short Bs[128 * 128];
    __shared__ int sidx[256];
    __shared__ float rowred2[2][128];
    const int tid = threadIdx.x;
    const int qb = blockIdx.x * 128;
    if (tid < 256) {
        const int rr = tid & 127;
        const int q = qb + rr;
        sidx[tid] = (q < nq) ? eli[(tid >> 7) * NQ + q] : 0;
    }
    __syncthreads();

    const int lane = tid & 63;
    const int wid = tid >> 6;
    const int wm = wid >> 1, wn = wid & 1;

    f32x4 acc[2][4];
    #pragma unroll
    for (int mf = 0; mf < 2; ++mf)
        #pragma unroll
        for (int nf = 0; nf < 4; ++nf) acc[mf][nf] = (f32x4){0.f, 0.f, 0.f, 0.f};

    #pragma unroll
    for (int s = 0; s < 2; ++s) {
        if (s) __syncthreads();
        #pragma unroll
        for (int i = 0; i < 4; ++i) {
            const int r = i * 32 + (tid >> 4);
            const int p = tid & 15;
            const int node = sidx[s * 128 + r];
            const int gc = p ^ (r & 7);
            const uint4 v = *(const uint4*)(xf + (size_t)node * 128 + gc * 8);
            *(uint4*)(As + r * 128 + p * 8) = v;
        }
        #pragma unroll
        for (int i = 0; i < 4; ++i) {
            const int n = i * 32 + (tid >> 4);
            const int p = tid & 15;
            const int gc = s * 16 + (p ^ (n & 7));
            const uint4 v = *(const uint4*)(Wtm + (size_t)n * 256 + gc * 8);
            *(uint4*)(Bs + n * 128 + p * 8) = v;
        }
        __syncthreads();
        #pragma unroll
        for (int kk = 0; kk < 4; ++kk) {
            short8 a[2], b[4];
            #pragma unroll
            for (int mf = 0; mf < 2; ++mf) {
                const int r = wm * 32 + mf * 16 + (lane & 15);
                const int p = (kk * 4 + (lane >> 4)) ^ (r & 7);
                a[mf] = *(const short8*)(As + r * 128 + p * 8);
            }
            #pragma unroll
            for (int nf = 0; nf < 4; ++nf) {
                const int n = wn * 64 + nf * 16 + (lane & 15);
                const int p = (kk * 4 + (lane >> 4)) ^ (n & 7);
                b[nf] = *(const short8*)(Bs + n * 128 + p * 8);
            }
            #pragma unroll
            for (int mf = 0; mf < 2; ++mf)
                #pragma unroll
                for (int nf = 0; nf < 4; ++nf)
                    acc[mf][nf] = __builtin_amdgcn_mfma_f32_16x16x32_bf16(
                        a[mf], b[nf], acc[mf][nf], 0, 0, 0);
        }
    }

    int colv[4];
    float w2v[4], b1c[4];
    #pragma unroll
    for (int nf = 0; nf < 4; ++nf) {
        colv[nf] = wn * 64 + nf * 16 + (lane & 15);
        w2v[nf] = w2[colv[nf]];
        b1c[nf] = b1v[colv[nf]];
    }
    #pragma unroll
    for (int mf = 0; mf < 2; ++mf) {
        #pragma unroll
        for (int reg = 0; reg < 4; ++reg) {
            float part = 0.f;
            #pragma unroll
            for (int nf = 0; nf < 4; ++nf)
                part += gelu_f(acc[mf][nf][reg] + b1c[nf]) * w2v[nf];
            part += __shfl_xor(part, 1);
            part += __shfl_xor(part, 2);
            part += __shfl_xor(part, 4);
            part += __shfl_xor(part, 8);
            if ((lane & 15) == 0) {
                const int lr = wm * 32 + mf * 16 + (lane >> 4) * 4 + reg;
                rowred2[wn][lr] = part;  // unique writer per (wn, lr)
            }
        }
    }
    __syncthreads();
    if (tid < 128) {
        const int q = qb + tid;
        if (q < nq)
            out[q] = 1.0f / (1.0f + expf(-(rowred2[0][tid] + rowred2[1][tid] + b2[0])));
    }
}

// ---------------- launcher ----------------

extern "C" void kernel_launch(void* const* d_in, const int* in_sizes, int n_in,
                              void* d_out, int out_size, void* d_ws, size_t ws_size,
                              hipStream_t stream) {
    const float* x_in = (const float*)d_in[0];
    const int* ei = (const int*)d_in[1];
    const float* ea = (const float*)d_in[2];
    const int* eli = (const int*)d_in[3];
    const float* rel_w = (const float*)d_in[4];
    const float* rel_b = (const float*)d_in[5];
    const float* root_w = (const float*)d_in[6];
    const float* bn_g = (const float*)d_in[7];
    const float* bn_b = (const float*)d_in[8];
    const float* w1 = (const float*)d_in[9];
    const float* b1 = (const float*)d_in[10];
    const float* w2 = (const float*)d_in[11];
    const float* b2 = (const float*)d_in[12];
    float* out = (float*)d_out;

    char* ws = (char*)d_ws;
    size_t off = 0;
    auto alloc = [&](size_t bytes) -> void* {
        void* p = ws + off;
        off = (off + bytes + 255) & ~(size_t)255;
        return p;
    };
    const int nblk_gemm = (NN + 127) / 128;  // 782
    unsigned short* hb0 = (unsigned short*)alloc(2ull * NN * HID);
    unsigned short* hb1 = (unsigned short*)alloc(2ull * NN * HID);
    unsigned short* aggb = (unsigned short*)alloc(2ull * NN * HID);
    int* eord = (int*)alloc(sizeof(int) * EE);
    int* csrc = (int*)alloc(sizeof(int) * EE);
    float* cea = (float*)alloc(sizeof(float) * EE);
    int* rp = (int*)alloc(sizeof(int) * (NN + 1));
    int* cnt = (int*)alloc(sizeof(int) * NN);
    int* bsum = (int*)alloc(sizeof(int) * 256);
    float* wdeg = (float*)alloc(sizeof(float) * NN);
    float* bnpart = (float*)alloc(sizeof(float) * 256 * (size_t)nblk_gemm);
    float* bn = (float*)alloc(sizeof(float) * 256);
    float* bnsc = (float*)alloc(sizeof(float) * 256);
    unsigned short* Wt = (unsigned short*)alloc(2ull * 128 * 256);
    unsigned short* Wtm = (unsigned short*)alloc(2ull * 128 * 256);
    float* bias2 = (float*)alloc(sizeof(float) * 128);
    float* brel = (float*)alloc(sizeof(float) * 128);
    float* b1v = (float*)alloc(sizeof(float) * 128);
    (void)ws_size;

    const int nb_scan = (NN + 1023) / 1024;

    // input -> bf16
    k_cvt<<<(NN * 64 + 255) / 256, 256, 0, stream>>>(x_in, (unsigned int*)hb0, NN * 64);

    // CSR build (deterministic final arrays)
    k_zero_int<<<(NN + 255) / 256, 256, 0, stream>>>(cnt, NN);
    k_hist<<<(EE + 255) / 256, 256, 0, stream>>>(ei, cnt);
    k_scan1<<<nb_scan, 256, 0, stream>>>(cnt, rp, bsum, NN);
    k_scan2<<<1, 256, 0, stream>>>(bsum, nb_scan);
    k_scan3<<<(NN + 255) / 256, 256, 0, stream>>>(rp, bsum, cnt, NN);
    k_fill<<<(EE + 255) / 256, 256, 0, stream>>>(ei, rp, cnt, eord);
    k_sortfill<<<(NN + 255) / 256, 256, 0, stream>>>(ei, ea, rp, eord, csrc, cea, wdeg);
    k_bninit<<<1, 256, 0, stream>>>(bnsc);

    unsigned short* hcur = hb0;
    unsigned short* bufs[2] = {hb1, hb0};
    for (int l = 0; l < NL; ++l) {
        unsigned short* hnext = bufs[l & 1];
        k_wprep<<<128, 256, 0, stream>>>(rel_w + (size_t)l * HID * HID,
                                         root_w + (size_t)l * HID * HID,
                                         rel_b + (size_t)l * HID, bnsc, Wt, bias2, brel);
        k_gather<<<2048, 256, 0, stream>>>(hcur, csrc, cea, rp, aggb);
        k_gemm2<<<nblk_gemm, 512, 0, stream>>>(aggb, hcur, Wt, bias2, brel, wdeg,
                                               hnext, bnpart, NN, nblk_gemm);
        k_bnred<<<256, 256, 0, stream>>>(bnpart, nblk_gemm, bn);
        k_bnfin<<<1, 128, 0, stream>>>(bn, bn_g + (size_t)l * HID, bn_b + (size_t)l * HID, bnsc);
        hcur = hnext;
    }

    k_mlpprep<<<128, 256, 0, stream>>>(w1, b1, bnsc, Wtm, b1v);
    k_mlp2<<<(NQ + 127) / 128, 512, 0, stream>>>(hcur, eli, Wtm, b1v, w2, b2, out, NQ);
}

// Round 7
// 544.020 us; speedup vs baseline: 2.6401x; 1.0735x over previous
//
#include <hip/hip_runtime.h>

#define NN 100000
#define EE 600000
#define NQ 200000
#define HID 128
#define NL 4
#define BN_EPS 1e-5f

typedef __attribute__((ext_vector_type(8))) short short8;
typedef __attribute__((ext_vector_type(4))) float f32x4;

__device__ __forceinline__ float gelu_f(float v) {
    return 0.5f * v * (1.0f + erff(v * 0.70710678118654752f));
}
__device__ __forceinline__ unsigned short f2bf(float f) {
    unsigned int x = __float_as_uint(f);
    unsigned int r = (x + 0x7FFFu + ((x >> 16) & 1u)) >> 16;
    return (unsigned short)r;
}
__device__ __forceinline__ float bf2f(unsigned short u) {
    return __uint_as_float(((unsigned int)u) << 16);
}

// ---------------- small utility kernels ----------------

__global__ void k_zero_int(int* __restrict__ p, int n) {
    int i = blockIdx.x * blockDim.x + threadIdx.x;
    if (i < n) p[i] = 0;
}

__global__ void k_cvt(const float* __restrict__ x, unsigned int* __restrict__ o, int n2) {
    int i = blockIdx.x * blockDim.x + threadIdx.x;
    if (i < n2) {
        float2 v = ((const float2*)x)[i];
        o[i] = (unsigned int)f2bf(v.x) | ((unsigned int)f2bf(v.y) << 16);
    }
}

__global__ void k_bninit(float* __restrict__ sc) {
    int i = threadIdx.x;
    sc[i] = (i < 128) ? 1.0f : 0.0f;
}

// ---------------- CSR build (deterministic) ----------------

__global__ void k_hist(const int* __restrict__ ei, int* __restrict__ cnt) {
    int e = blockIdx.x * blockDim.x + threadIdx.x;
    if (e < EE) atomicAdd(&cnt[ei[EE + e]], 1);  // int atomics: deterministic result
}

__global__ void k_scan1(const int* __restrict__ cnt, int* __restrict__ rp,
                        int* __restrict__ bsum, int n) {
    __shared__ int sh[256];
    const int tid = threadIdx.x;
    const int base = blockIdx.x * 1024;
    int v[4];
    int s = 0;
    #pragma unroll
    for (int j = 0; j < 4; ++j) {
        int idx = base + tid * 4 + j;
        v[j] = (idx < n) ? cnt[idx] : 0;
        s += v[j];
    }
    sh[tid] = s;
    __syncthreads();
    for (int off = 1; off < 256; off <<= 1) {
        int t = (tid >= off) ? sh[tid - off] : 0;
        __syncthreads();
        sh[tid] += t;
        __syncthreads();
    }
    int run = sh[tid] - s;
    #pragma unroll
    for (int j = 0; j < 4; ++j) {
        int idx = base + tid * 4 + j;
        if (idx < n) rp[idx] = run;
        run += v[j];
    }
    if (tid == 255) bsum[blockIdx.x] = sh[255];
}

__global__ void k_scan2(int* __restrict__ bsum, int nb) {
    __shared__ int sh[256];
    const int tid = threadIdx.x;
    int v = (tid < nb) ? bsum[tid] : 0;
    sh[tid] = v;
    __syncthreads();
    for (int off = 1; off < 256; off <<= 1) {
        int t = (tid >= off) ? sh[tid - off] : 0;
        __syncthreads();
        sh[tid] += t;
        __syncthreads();
    }
    if (tid < nb) bsum[tid] = sh[tid] - v;
}

__global__ void k_scan3(int* __restrict__ rp, const int* __restrict__ bsum,
                        int* __restrict__ cnt, int n) {
    int i = blockIdx.x * blockDim.x + threadIdx.x;
    if (i < n) {
        rp[i] += bsum[i >> 10];
        cnt[i] = 0;
    }
    if (i == 0) rp[n] = EE;
}

// slot assignment is atomic-order-dependent; only edge ids are stored here
__global__ void k_fill(const int* __restrict__ ei, const int* __restrict__ rp,
                       int* __restrict__ cur, int* __restrict__ eord) {
    int e = blockIdx.x * blockDim.x + threadIdx.x;
    if (e < EE) {
        int d = ei[EE + e];
        int p = rp[d] + atomicAdd(&cur[d], 1);
        eord[p] = e;
    }
}

// canonicalize: sort each segment by edge id, then materialize csrc/cea/wdeg.
__global__ void k_sortfill(const int* __restrict__ ei, const float* __restrict__ ea,
                           const int* __restrict__ rp, int* __restrict__ eord,
                           int* __restrict__ csrc, float* __restrict__ cea,
                           float* __restrict__ wdeg) {
    int n = blockIdx.x * blockDim.x + threadIdx.x;
    if (n >= NN) return;
    const int s0 = rp[n], s1 = rp[n + 1];
    for (int i = s0 + 1; i < s1; ++i) {
        int key = eord[i];
        int j = i - 1;
        while (j >= s0 && eord[j] > key) { eord[j + 1] = eord[j]; --j; }
        eord[j + 1] = key;
    }
    float s = 0.f;
    for (int i = s0; i < s1; ++i) {
        const int e = eord[i];
        csrc[i] = ei[e];
        const float w = ea[e];
        cea[i] = w;
        s += w;
    }
    wdeg[n] = s;
}

// ---------------- weight prep (parallel, BN affine folded) ----------------

__global__ void k_wprep(const float* __restrict__ relw, const float* __restrict__ rootw,
                        const float* __restrict__ relb, const float* __restrict__ sc,
                        unsigned short* __restrict__ Wt, float* __restrict__ bias2,
                        float* __restrict__ brel) {
    __shared__ float shb[256];
    const int n = blockIdx.x;
    const int k = threadIdx.x;
    const float s = sc[k & 127];
    const float w = (k < 128) ? relw[(size_t)k * HID + n] : rootw[(size_t)(k - 128) * HID + n];
    Wt[(size_t)n * 256 + k] = f2bf(s * w);
    shb[k] = sc[128 + (k & 127)] * w;
    __syncthreads();
    #pragma unroll
    for (int off = 64; off >= 1; off >>= 1) {
        if (k < off) shb[k] += shb[k + off];
        else if (k >= 128 && k < 128 + off) shb[k] += shb[k + off];
        __syncthreads();
    }
    if (k == 0) brel[n] = shb[0];
    if (k == 128) bias2[n] = relb[n] + shb[128];
}

__global__ void k_mlpprep(const float* __restrict__ w1, const float* __restrict__ b1,
                          const float* __restrict__ sc, unsigned short* __restrict__ Wtm,
                          float* __restrict__ b1v) {
    __shared__ float shb[256];
    const int n = blockIdx.x;
    const int k = threadIdx.x;
    const float w = w1[(size_t)k * HID + n];
    Wtm[(size_t)n * 256 + k] = f2bf(sc[k & 127] * w);
    shb[k] = sc[128 + (k & 127)] * w;
    __syncthreads();
    #pragma unroll
    for (int off = 128; off >= 1; off >>= 1) {
        if (k < off) shb[k] += shb[k + off];
        __syncthreads();
    }
    if (k == 0) b1v[n] = b1[n] + shb[0];
}

// ---------------- fused gather + MFMA conv GEMM ----------------
// s=0 A-tile is built by gathering edges directly (CSR is dst-ordered, so the
// block's 128 rows own the contiguous edge range rp[rb]..rp[rb+128]).
// Per row: 4 lane-groups process 4 edges in flight; 16 lanes x 16B cover the row.
// Fixed-order shfl_xor combine keeps it deterministic.

__global__ __launch_bounds__(512, 4) void k_gemm2(
    const unsigned short* __restrict__ hprev, const int* __restrict__ csrc,
    const float* __restrict__ cea, const int* __restrict__ rp,
    const unsigned short* __restrict__ Wt, const float* __restrict__ bias2,
    const float* __restrict__ brel, const float* __restrict__ wdeg,
    unsigned short* __restrict__ hnext, float* __restrict__ bnpart,
    int nrows, int nblk) {
    __shared__ unsigned short As[128 * 128];
    __shared__ unsigned short Bs[128 * 128];
    __shared__ float psb[8 * 64];
    __shared__ float pqb[8 * 64];
    const int tid = threadIdx.x;
    const int rb = blockIdx.x * 128;

    const int lane = tid & 63;
    const int wid = tid >> 6;
    const int wm = wid >> 1, wn = wid & 1;

    f32x4 acc[2][4];
    #pragma unroll
    for (int mf = 0; mf < 2; ++mf)
        #pragma unroll
        for (int nf = 0; nf < 4; ++nf) acc[mf][nf] = (f32x4){0.f, 0.f, 0.f, 0.f};

    #pragma unroll
    for (int s = 0; s < 2; ++s) {
        if (s) __syncthreads();
        if (s == 0) {
            // ---- gather-staging: wave w owns rows w*16 .. w*16+15 ----
            const int g = lane >> 4;        // edge sub-group 0..3
            const int cl = lane & 15;       // 16B chunk within the row
            for (int rr = 0; rr < 16; ++rr) {
                const int r = wid * 16 + rr;
                const int n = rb + r;
                int s0 = 0, s1 = 0;
                if (n < nrows) { s0 = rp[n]; s1 = rp[n + 1]; }
                float a0 = 0.f, a1 = 0.f, a2 = 0.f, a3 = 0.f,
                      a4 = 0.f, a5 = 0.f, a6 = 0.f, a7 = 0.f;
                for (int i = s0 + g; i < s1; i += 4) {
                    const int src = csrc[i];
                    const float w = cea[i];
                    const uint4 v = *(const uint4*)(hprev + (size_t)src * HID + cl * 8);
                    a0 += bf2f((unsigned short)(v.x)) * w;
                    a1 += bf2f((unsigned short)(v.x >> 16)) * w;
                    a2 += bf2f((unsigned short)(v.y)) * w;
                    a3 += bf2f((unsigned short)(v.y >> 16)) * w;
                    a4 += bf2f((unsigned short)(v.z)) * w;
                    a5 += bf2f((unsigned short)(v.z >> 16)) * w;
                    a6 += bf2f((unsigned short)(v.w)) * w;
                    a7 += bf2f((unsigned short)(v.w >> 16)) * w;
                }
                // fixed-order cross-group combine: (g^1 then g^2) — deterministic tree
                a0 += __shfl_xor(a0, 16); a1 += __shfl_xor(a1, 16);
                a2 += __shfl_xor(a2, 16); a3 += __shfl_xor(a3, 16);
                a4 += __shfl_xor(a4, 16); a5 += __shfl_xor(a5, 16);
                a6 += __shfl_xor(a6, 16); a7 += __shfl_xor(a7, 16);
                a0 += __shfl_xor(a0, 32); a1 += __shfl_xor(a1, 32);
                a2 += __shfl_xor(a2, 32); a3 += __shfl_xor(a3, 32);
                a4 += __shfl_xor(a4, 32); a5 += __shfl_xor(a5, 32);
                a6 += __shfl_xor(a6, 32); a7 += __shfl_xor(a7, 32);
                if (g == 0) {
                    uint4 o;
                    o.x = (unsigned int)f2bf(a0) | ((unsigned int)f2bf(a1) << 16);
                    o.y = (unsigned int)f2bf(a2) | ((unsigned int)f2bf(a3) << 16);
                    o.z = (unsigned int)f2bf(a4) | ((unsigned int)f2bf(a5) << 16);
                    o.w = (unsigned int)f2bf(a6) | ((unsigned int)f2bf(a7) << 16);
                    const int p = cl ^ (r & 7);  // swizzled chunk position
                    *(uint4*)(As + r * 128 + p * 8) = o;
                }
            }
        } else {
            // ---- contiguous hprev staging (root path) ----
            #pragma unroll
            for (int i = 0; i < 4; ++i) {
                const int r = i * 32 + (tid >> 4);
                const int p = tid & 15;
                const int gr = min(rb + r, nrows - 1);
                const int gc = p ^ (r & 7);
                const uint4 v = *(const uint4*)(hprev + (size_t)gr * 128 + gc * 8);
                *(uint4*)(As + r * 128 + p * 8) = v;
            }
        }
        #pragma unroll
        for (int i = 0; i < 4; ++i) {
            const int n = i * 32 + (tid >> 4);
            const int p = tid & 15;
            const int gc = s * 16 + (p ^ (n & 7));
            const uint4 v = *(const uint4*)(Wt + (size_t)n * 256 + gc * 8);
            *(uint4*)(Bs + n * 128 + p * 8) = v;
        }
        __syncthreads();
        #pragma unroll
        for (int kk = 0; kk < 4; ++kk) {
            short8 a[2], b[4];
            #pragma unroll
            for (int mf = 0; mf < 2; ++mf) {
                const int r = wm * 32 + mf * 16 + (lane & 15);
                const int p = (kk * 4 + (lane >> 4)) ^ (r & 7);
                a[mf] = *(const short8*)(As + r * 128 + p * 8);
            }
            #pragma unroll
            for (int nf = 0; nf < 4; ++nf) {
                const int n = wn * 64 + nf * 16 + (lane & 15);
                const int p = (kk * 4 + (lane >> 4)) ^ (n & 7);
                b[nf] = *(const short8*)(Bs + n * 128 + p * 8);
            }
            #pragma unroll
            for (int mf = 0; mf < 2; ++mf)
                #pragma unroll
                for (int nf = 0; nf < 4; ++nf)
                    acc[mf][nf] = __builtin_amdgcn_mfma_f32_16x16x32_bf16(
                        a[mf], b[nf], acc[mf][nf], 0, 0, 0);
        }
    }

    // epilogue: bias + wdeg*brel, gelu, store bf16, BN partials (fixed order, no atomics)
    int colv[4];
    float biasv[4], brelv[4];
    #pragma unroll
    for (int nf = 0; nf < 4; ++nf) {
        colv[nf] = wn * 64 + nf * 16 + (lane & 15);
        biasv[nf] = bias2[colv[nf]];
        brelv[nf] = brel[colv[nf]];
    }
    float ps[4] = {0.f, 0.f, 0.f, 0.f}, pq[4] = {0.f, 0.f, 0.f, 0.f};
    #pragma unroll
    for (int mf = 0; mf < 2; ++mf) {
        #pragma unroll
        for (int reg = 0; reg < 4; ++reg) {
            const int gm = rb + wm * 32 + mf * 16 + (lane >> 4) * 4 + reg;
            const bool valid = gm < nrows;
            const float wd = valid ? wdeg[gm] : 0.f;
            #pragma unroll
            for (int nf = 0; nf < 4; ++nf) {
                const float hv = gelu_f(acc[mf][nf][reg] + biasv[nf] + wd * brelv[nf]);
                if (valid) {
                    hnext[(size_t)gm * 128 + colv[nf]] = f2bf(hv);
                    ps[nf] += hv;
                    pq[nf] += hv * hv;
                }
            }
        }
    }
    #pragma unroll
    for (int nf = 0; nf < 4; ++nf) {
        ps[nf] += __shfl_xor(ps[nf], 16); ps[nf] += __shfl_xor(ps[nf], 32);
        pq[nf] += __shfl_xor(pq[nf], 16); pq[nf] += __shfl_xor(pq[nf], 32);
        if ((lane >> 4) == 0) {
            psb[wid * 64 + nf * 16 + (lane & 15)] = ps[nf];
            pqb[wid * 64 + nf * 16 + (lane & 15)] = pq[nf];
        }
    }
    __syncthreads();
    if (tid < 128) {
        const int wnh = tid >> 6;
        const int c64 = tid & 63;
        float s = 0.f, q = 0.f;
        #pragma unroll
        for (int w = 0; w < 4; ++w) {  // fixed order across waves
            s += psb[(w * 2 + wnh) * 64 + c64];
            q += pqb[(w * 2 + wnh) * 64 + c64];
        }
        bnpart[(size_t)tid * nblk + blockIdx.x] = s;
        bnpart[(size_t)(128 + tid) * nblk + blockIdx.x] = q;
    }
}

// parallel deterministic reduce: one block per column, coalesced reads, fixed-order tree
__global__ void k_bnred(const float* __restrict__ bnpart, int nblk, float* __restrict__ bn) {
    __shared__ float sh[256];
    const int tid = threadIdx.x;
    const int col = blockIdx.x;
    float s = 0.f;
    for (int i = tid; i < nblk; i += 256) s += bnpart[(size_t)col * nblk + i];
    sh[tid] = s;
    __syncthreads();
    #pragma unroll
    for (int off = 128; off >= 1; off >>= 1) {
        if (tid < off) sh[tid] += sh[tid + off];
        __syncthreads();
    }
    if (tid == 0) bn[col] = sh[0];
}

__global__ void k_bnfin(const float* __restrict__ bn, const float* __restrict__ g,
                        const float* __restrict__ b, float* __restrict__ sc) {
    int i = threadIdx.x;
    if (i < 128) {
        const float inv_n = 1.0f / (float)NN;
        const float mean = bn[i] * inv_n;
        const float var = bn[128 + i] * inv_n - mean * mean;
        const float s = g[i] * rsqrtf(var + BN_EPS);
        sc[i] = s;
        sc[128 + i] = b[i] - mean * s;
    }
}

// ---------------- MFMA edge MLP (deterministic row reduce) ----------------

__global__ __launch_bounds__(512, 4) void k_mlp2(
    const unsigned short* __restrict__ xf, const int* __restrict__ eli,
    const unsigned short* __restrict__ Wtm, const float* __restrict__ b1v,
    const float* __restrict__ w2, const float* __restrict__ b2,
    float* __restrict__ out, int nq) {
    __shared__ unsigned short As[128 * 128];
    __shared__ unsigned short Bs[128 * 128];
    __shared__ int sidx[256];
    __shared__ float rowred2[2][128];
    const int tid = threadIdx.x;
    const int qb = blockIdx.x * 128;
    if (tid < 256) {
        const int rr = tid & 127;
        const int q = qb + rr;
        sidx[tid] = (q < nq) ? eli[(tid >> 7) * NQ + q] : 0;
    }
    __syncthreads();

    const int lane = tid & 63;
    const int wid = tid >> 6;
    const int wm = wid >> 1, wn = wid & 1;

    f32x4 acc[2][4];
    #pragma unroll
    for (int mf = 0; mf < 2; ++mf)
        #pragma unroll
        for (int nf = 0; nf < 4; ++nf) acc[mf][nf] = (f32x4){0.f, 0.f, 0.f, 0.f};

    #pragma unroll
    for (int s = 0; s < 2; ++s) {
        if (s) __syncthreads();
        #pragma unroll
        for (int i = 0; i < 4; ++i) {
            const int r = i * 32 + (tid >> 4);
            const int p = tid & 15;
            const int node = sidx[s * 128 + r];
            const int gc = p ^ (r & 7);
            const uint4 v = *(const uint4*)(xf + (size_t)node * 128 + gc * 8);
            *(uint4*)(As + r * 128 + p * 8) = v;
        }
        #pragma unroll
        for (int i = 0; i < 4; ++i) {
            const int n = i * 32 + (tid >> 4);
            const int p = tid & 15;
            const int gc = s * 16 + (p ^ (n & 7));
            const uint4 v = *(const uint4*)(Wtm + (size_t)n * 256 + gc * 8);
            *(uint4*)(Bs + n * 128 + p * 8) = v;
        }
        __syncthreads();
        #pragma unroll
        for (int kk = 0; kk < 4; ++kk) {
            short8 a[2], b[4];
            #pragma unroll
            for (int mf = 0; mf < 2; ++mf) {
                const int r = wm * 32 + mf * 16 + (lane & 15);
                const int p = (kk * 4 + (lane >> 4)) ^ (r & 7);
                a[mf] = *(const short8*)(As + r * 128 + p * 8);
            }
            #pragma unroll
            for (int nf = 0; nf < 4; ++nf) {
                const int n = wn * 64 + nf * 16 + (lane & 15);
                const int p = (kk * 4 + (lane >> 4)) ^ (n & 7);
                b[nf] = *(const short8*)(Bs + n * 128 + p * 8);
            }
            #pragma unroll
            for (int mf = 0; mf < 2; ++mf)
                #pragma unroll
                for (int nf = 0; nf < 4; ++nf)
                    acc[mf][nf] = __builtin_amdgcn_mfma_f32_16x16x32_bf16(
                        a[mf], b[nf], acc[mf][nf], 0, 0, 0);
        }
    }

    int colv[4];
    float w2v[4], b1c[4];
    #pragma unroll
    for (int nf = 0; nf < 4; ++nf) {
        colv[nf] = wn * 64 + nf * 16 + (lane & 15);
        w2v[nf] = w2[colv[nf]];
        b1c[nf] = b1v[colv[nf]];
    }
    #pragma unroll
    for (int mf = 0; mf < 2; ++mf) {
        #pragma unroll
        for (int reg = 0; reg < 4; ++reg) {
            float part = 0.f;
            #pragma unroll
            for (int nf = 0; nf < 4; ++nf)
                part += gelu_f(acc[mf][nf][reg] + b1c[nf]) * w2v[nf];
            part += __shfl_xor(part, 1);
            part += __shfl_xor(part, 2);
            part += __shfl_xor(part, 4);
            part += __shfl_xor(part, 8);
            if ((lane & 15) == 0) {
                const int lr = wm * 32 + mf * 16 + (lane >> 4) * 4 + reg;
                rowred2[wn][lr] = part;  // unique writer per (wn, lr)
            }
        }
    }
    __syncthreads();
    if (tid < 128) {
        const int q = qb + tid;
        if (q < nq)
            out[q] = 1.0f / (1.0f + expf(-(rowred2[0][tid] + rowred2[1][tid] + b2[0])));
    }
}

// ---------------- launcher ----------------

extern "C" void kernel_launch(void* const* d_in, const int* in_sizes, int n_in,
                              void* d_out, int out_size, void* d_ws, size_t ws_size,
                              hipStream_t stream) {
    const float* x_in = (const float*)d_in[0];
    const int* ei = (const int*)d_in[1];
    const float* ea = (const float*)d_in[2];
    const int* eli = (const int*)d_in[3];
    const float* rel_w = (const float*)d_in[4];
    const float* rel_b = (const float*)d_in[5];
    const float* root_w = (const float*)d_in[6];
    const float* bn_g = (const float*)d_in[7];
    const float* bn_b = (const float*)d_in[8];
    const float* w1 = (const float*)d_in[9];
    const float* b1 = (const float*)d_in[10];
    const float* w2 = (const float*)d_in[11];
    const float* b2 = (const float*)d_in[12];
    float* out = (float*)d_out;

    char* ws = (char*)d_ws;
    size_t off = 0;
    auto alloc = [&](size_t bytes) -> void* {
        void* p = ws + off;
        off = (off + bytes + 255) & ~(size_t)255;
        return p;
    };
    const int nblk_gemm = (NN + 127) / 128;  // 782
    unsigned short* hb0 = (unsigned short*)alloc(2ull * NN * HID);
    unsigned short* hb1 = (unsigned short*)alloc(2ull * NN * HID);
    int* eord = (int*)alloc(sizeof(int) * EE);
    int* csrc = (int*)alloc(sizeof(int) * EE);
    float* cea = (float*)alloc(sizeof(float) * EE);
    int* rp = (int*)alloc(sizeof(int) * (NN + 1));
    int* cnt = (int*)alloc(sizeof(int) * NN);
    int* bsum = (int*)alloc(sizeof(int) * 256);
    float* wdeg = (float*)alloc(sizeof(float) * NN);
    float* bnpart = (float*)alloc(sizeof(float) * 256 * (size_t)nblk_gemm);
    float* bn = (float*)alloc(sizeof(float) * 256);
    float* bnsc = (float*)alloc(sizeof(float) * 256);
    unsigned short* Wt = (unsigned short*)alloc(2ull * 128 * 256);
    unsigned short* Wtm = (unsigned short*)alloc(2ull * 128 * 256);
    float* bias2 = (float*)alloc(sizeof(float) * 128);
    float* brel = (float*)alloc(sizeof(float) * 128);
    float* b1v = (float*)alloc(sizeof(float) * 128);
    (void)ws_size;

    const int nb_scan = (NN + 1023) / 1024;

    // input -> bf16
    k_cvt<<<(NN * 64 + 255) / 256, 256, 0, stream>>>(x_in, (unsigned int*)hb0, NN * 64);

    // CSR build (deterministic final arrays)
    k_zero_int<<<(NN + 255) / 256, 256, 0, stream>>>(cnt, NN);
    k_hist<<<(EE + 255) / 256, 256, 0, stream>>>(ei, cnt);
    k_scan1<<<nb_scan, 256, 0, stream>>>(cnt, rp, bsum, NN);
    k_scan2<<<1, 256, 0, stream>>>(bsum, nb_scan);
    k_scan3<<<(NN + 255) / 256, 256, 0, stream>>>(rp, bsum, cnt, NN);
    k_fill<<<(EE + 255) / 256, 256, 0, stream>>>(ei, rp, cnt, eord);
    k_sortfill<<<(NN + 255) / 256, 256, 0, stream>>>(ei, ea, rp, eord, csrc, cea, wdeg);
    k_bninit<<<1, 256, 0, stream>>>(bnsc);

    unsigned short* hcur = hb0;
    unsigned short* bufs[2] = {hb1, hb0};
    for (int l = 0; l < NL; ++l) {
        unsigned short* hnext = bufs[l & 1];
        k_wprep<<<128, 256, 0, stream>>>(rel_w + (size_t)l * HID * HID,
                                         root_w + (size_t)l * HID * HID,
                                         rel_b + (size_t)l * HID, bnsc, Wt, bias2, brel);
        k_gemm2<<<nblk_gemm, 512, 0, stream>>>(hcur, csrc, cea, rp, Wt, bias2, brel, wdeg,
                                               hnext, bnpart, NN, nblk_gemm);
        k_bnred<<<256, 256, 0, stream>>>(bnpart, nblk_gemm, bn);
        k_bnfin<<<1, 128, 0, stream>>>(bn, bn_g + (size_t)l * HID, bn_b + (size_t)l * HID, bnsc);
        hcur = hnext;
    }

    k_mlpprep<<<128, 256, 0, stream>>>(w1, b1, bnsc, Wtm, b1v);
    k_mlp2<<<(NQ + 127) / 128, 512, 0, stream>>>(hcur, eli, Wtm, b1v, w2, b2, out, NQ);
}

// Round 8
// 466.584 us; speedup vs baseline: 3.0783x; 1.1660x over previous
//
#include <hip/hip_runtime.h>

#define NN 100000
#define EE 600000
#define NQ 200000
#define HID 128
#define NL 4
#define BN_EPS 1e-5f
#define ECAP 1280  // LDS edge-staging capacity (10 KB); fallback to global if exceeded

typedef __attribute__((ext_vector_type(8))) short short8;
typedef __attribute__((ext_vector_type(4))) float f32x4;

__device__ __forceinline__ float gelu_f(float v) {
    return 0.5f * v * (1.0f + erff(v * 0.70710678118654752f));
}
__device__ __forceinline__ unsigned short f2bf(float f) {
    unsigned int x = __float_as_uint(f);
    unsigned int r = (x + 0x7FFFu + ((x >> 16) & 1u)) >> 16;
    return (unsigned short)r;
}
__device__ __forceinline__ float bf2f(unsigned short u) {
    return __uint_as_float(((unsigned int)u) << 16);
}

// ---------------- small utility kernels ----------------

__global__ void k_zero_int(int* __restrict__ p, int n) {
    int i = blockIdx.x * blockDim.x + threadIdx.x;
    if (i < n) p[i] = 0;
}

__global__ void k_cvt(const float* __restrict__ x, unsigned int* __restrict__ o, int n2) {
    int i = blockIdx.x * blockDim.x + threadIdx.x;
    if (i < n2) {
        float2 v = ((const float2*)x)[i];
        o[i] = (unsigned int)f2bf(v.x) | ((unsigned int)f2bf(v.y) << 16);
    }
}

__global__ void k_bninit(float* __restrict__ sc) {
    int i = threadIdx.x;
    sc[i] = (i < 128) ? 1.0f : 0.0f;
}

// ---------------- CSR build (deterministic) ----------------

__global__ void k_hist(const int* __restrict__ ei, int* __restrict__ cnt) {
    int e = blockIdx.x * blockDim.x + threadIdx.x;
    if (e < EE) atomicAdd(&cnt[ei[EE + e]], 1);  // int atomics: deterministic result
}

__global__ void k_scan1(const int* __restrict__ cnt, int* __restrict__ rp,
                        int* __restrict__ bsum, int n) {
    __shared__ int sh[256];
    const int tid = threadIdx.x;
    const int base = blockIdx.x * 1024;
    int v[4];
    int s = 0;
    #pragma unroll
    for (int j = 0; j < 4; ++j) {
        int idx = base + tid * 4 + j;
        v[j] = (idx < n) ? cnt[idx] : 0;
        s += v[j];
    }
    sh[tid] = s;
    __syncthreads();
    for (int off = 1; off < 256; off <<= 1) {
        int t = (tid >= off) ? sh[tid - off] : 0;
        __syncthreads();
        sh[tid] += t;
        __syncthreads();
    }
    int run = sh[tid] - s;
    #pragma unroll
    for (int j = 0; j < 4; ++j) {
        int idx = base + tid * 4 + j;
        if (idx < n) rp[idx] = run;
        run += v[j];
    }
    if (tid == 255) bsum[blockIdx.x] = sh[255];
}

__global__ void k_scan2(int* __restrict__ bsum, int nb) {
    __shared__ int sh[256];
    const int tid = threadIdx.x;
    int v = (tid < nb) ? bsum[tid] : 0;
    sh[tid] = v;
    __syncthreads();
    for (int off = 1; off < 256; off <<= 1) {
        int t = (tid >= off) ? sh[tid - off] : 0;
        __syncthreads();
        sh[tid] += t;
        __syncthreads();
    }
    if (tid < nb) bsum[tid] = sh[tid] - v;
}

__global__ void k_scan3(int* __restrict__ rp, const int* __restrict__ bsum,
                        int* __restrict__ cnt, int n) {
    int i = blockIdx.x * blockDim.x + threadIdx.x;
    if (i < n) {
        rp[i] += bsum[i >> 10];
        cnt[i] = 0;
    }
    if (i == 0) rp[n] = EE;
}

// slot assignment is atomic-order-dependent; only edge ids are stored here
__global__ void k_fill(const int* __restrict__ ei, const int* __restrict__ rp,
                       int* __restrict__ cur, int* __restrict__ eord) {
    int e = blockIdx.x * blockDim.x + threadIdx.x;
    if (e < EE) {
        int d = ei[EE + e];
        int p = rp[d] + atomicAdd(&cur[d], 1);
        eord[p] = e;
    }
}

// canonicalize: sort each segment by edge id, then materialize csrc/cea/wdeg.
__global__ void k_sortfill(const int* __restrict__ ei, const float* __restrict__ ea,
                           const int* __restrict__ rp, int* __restrict__ eord,
                           int* __restrict__ csrc, float* __restrict__ cea,
                           float* __restrict__ wdeg) {
    int n = blockIdx.x * blockDim.x + threadIdx.x;
    if (n >= NN) return;
    const int s0 = rp[n], s1 = rp[n + 1];
    for (int i = s0 + 1; i < s1; ++i) {
        int key = eord[i];
        int j = i - 1;
        while (j >= s0 && eord[j] > key) { eord[j + 1] = eord[j]; --j; }
        eord[j + 1] = key;
    }
    float s = 0.f;
    for (int i = s0; i < s1; ++i) {
        const int e = eord[i];
        csrc[i] = ei[e];
        const float w = ea[e];
        cea[i] = w;
        s += w;
    }
    wdeg[n] = s;
}

// ---------------- weight prep (parallel, BN affine folded) ----------------

__global__ void k_wprep(const float* __restrict__ relw, const float* __restrict__ rootw,
                        const float* __restrict__ relb, const float* __restrict__ sc,
                        unsigned short* __restrict__ Wt, float* __restrict__ bias2,
                        float* __restrict__ brel) {
    __shared__ float shb[256];
    const int n = blockIdx.x;
    const int k = threadIdx.x;
    const float s = sc[k & 127];
    const float w = (k < 128) ? relw[(size_t)k * HID + n] : rootw[(size_t)(k - 128) * HID + n];
    Wt[(size_t)n * 256 + k] = f2bf(s * w);
    shb[k] = sc[128 + (k & 127)] * w;
    __syncthreads();
    #pragma unroll
    for (int off = 64; off >= 1; off >>= 1) {
        if (k < off) shb[k] += shb[k + off];
        else if (k >= 128 && k < 128 + off) shb[k] += shb[k + off];
        __syncthreads();
    }
    if (k == 0) brel[n] = shb[0];
    if (k == 128) bias2[n] = relb[n] + shb[128];
}

__global__ void k_mlpprep(const float* __restrict__ w1, const float* __restrict__ b1,
                          const float* __restrict__ sc, unsigned short* __restrict__ Wtm,
                          float* __restrict__ b1v) {
    __shared__ float shb[256];
    const int n = blockIdx.x;
    const int k = threadIdx.x;
    const float w = w1[(size_t)k * HID + n];
    Wtm[(size_t)n * 256 + k] = f2bf(sc[k & 127] * w);
    shb[k] = sc[128 + (k & 127)] * w;
    __syncthreads();
    #pragma unroll
    for (int off = 128; off >= 1; off >>= 1) {
        if (k < off) shb[k] += shb[k + off];
        __syncthreads();
    }
    if (k == 0) b1v[n] = b1[n] + shb[0];
}

// ---------------- fused gather + MFMA conv GEMM ----------------
// Block's edge range rp[rb]..rp[rb+128] is contiguous; stage indices/weights in
// LDS (kills the global csrc->hprev dependent chain), 2-wide edge ILP per
// lane-group (2 hprev row loads in flight). Fixed-order combine = deterministic.

__global__ __launch_bounds__(512, 2) void k_gemm2(
    const unsigned short* __restrict__ hprev, const int* __restrict__ csrc,
    const float* __restrict__ cea, const int* __restrict__ rp,
    const unsigned short* __restrict__ Wt, const float* __restrict__ bias2,
    const float* __restrict__ brel, const float* __restrict__ wdeg,
    unsigned short* __restrict__ hnext, float* __restrict__ bnpart,
    int nrows, int nblk) {
    __shared__ unsigned short As[128 * 128];
    __shared__ unsigned short Bs[128 * 128];
    __shared__ float psb[8 * 64];
    __shared__ float pqb[8 * 64];
    __shared__ int eidx[ECAP];
    __shared__ float ew[ECAP];
    __shared__ int rps[132];
    const int tid = threadIdx.x;
    const int rb = blockIdx.x * 128;

    const int lane = tid & 63;
    const int wid = tid >> 6;
    const int wm = wid >> 1, wn = wid & 1;

    // stage row bounds + edge data
    if (tid < 129) {
        int nn = rb + tid;
        rps[tid] = rp[nn < nrows ? nn : nrows];
    }
    __syncthreads();
    const int e0 = rps[0];
    const int ne = rps[128] - e0;
    const bool useLds = (ne <= ECAP);
    if (useLds) {
        for (int i = tid; i < ne; i += 512) {
            eidx[i] = csrc[e0 + i];
            ew[i] = cea[e0 + i];
        }
    }

    f32x4 acc[2][4];
    #pragma unroll
    for (int mf = 0; mf < 2; ++mf)
        #pragma unroll
        for (int nf = 0; nf < 4; ++nf) acc[mf][nf] = (f32x4){0.f, 0.f, 0.f, 0.f};

    #pragma unroll
    for (int s = 0; s < 2; ++s) {
        __syncthreads();
        if (s == 0) {
            // ---- gather-staging: wave w owns rows w*16 .. w*16+15 ----
            const int g = lane >> 4;        // edge sub-group 0..3
            const int cl = lane & 15;       // 16B chunk within the row
            for (int rr = 0; rr < 16; ++rr) {
                const int r = wid * 16 + rr;
                const int s0 = rps[r] - e0, s1 = rps[r + 1] - e0;
                float a0 = 0.f, a1 = 0.f, a2 = 0.f, a3 = 0.f,
                      a4 = 0.f, a5 = 0.f, a6 = 0.f, a7 = 0.f;
                for (int i = s0 + g; i < s1; i += 8) {
                    const int i2 = i + 4;
                    const bool has2 = i2 < s1;
                    int src1, src2;
                    float w1, w2;
                    if (useLds) {
                        src1 = eidx[i]; w1 = ew[i];
                        src2 = has2 ? eidx[i2] : src1;
                        w2 = has2 ? ew[i2] : 0.f;
                    } else {
                        src1 = csrc[e0 + i]; w1 = cea[e0 + i];
                        src2 = has2 ? csrc[e0 + i2] : src1;
                        w2 = has2 ? cea[e0 + i2] : 0.f;
                    }
                    const uint4 va = *(const uint4*)(hprev + (size_t)src1 * HID + cl * 8);
                    const uint4 vb = *(const uint4*)(hprev + (size_t)src2 * HID + cl * 8);
                    a0 += bf2f((unsigned short)(va.x)) * w1;
                    a1 += bf2f((unsigned short)(va.x >> 16)) * w1;
                    a2 += bf2f((unsigned short)(va.y)) * w1;
                    a3 += bf2f((unsigned short)(va.y >> 16)) * w1;
                    a4 += bf2f((unsigned short)(va.z)) * w1;
                    a5 += bf2f((unsigned short)(va.z >> 16)) * w1;
                    a6 += bf2f((unsigned short)(va.w)) * w1;
                    a7 += bf2f((unsigned short)(va.w >> 16)) * w1;
                    a0 += bf2f((unsigned short)(vb.x)) * w2;
                    a1 += bf2f((unsigned short)(vb.x >> 16)) * w2;
                    a2 += bf2f((unsigned short)(vb.y)) * w2;
                    a3 += bf2f((unsigned short)(vb.y >> 16)) * w2;
                    a4 += bf2f((unsigned short)(vb.z)) * w2;
                    a5 += bf2f((unsigned short)(vb.z >> 16)) * w2;
                    a6 += bf2f((unsigned short)(vb.w)) * w2;
                    a7 += bf2f((unsigned short)(vb.w >> 16)) * w2;
                }
                // fixed-order cross-group combine — deterministic tree
                a0 += __shfl_xor(a0, 16); a1 += __shfl_xor(a1, 16);
                a2 += __shfl_xor(a2, 16); a3 += __shfl_xor(a3, 16);
                a4 += __shfl_xor(a4, 16); a5 += __shfl_xor(a5, 16);
                a6 += __shfl_xor(a6, 16); a7 += __shfl_xor(a7, 16);
                a0 += __shfl_xor(a0, 32); a1 += __shfl_xor(a1, 32);
                a2 += __shfl_xor(a2, 32); a3 += __shfl_xor(a3, 32);
                a4 += __shfl_xor(a4, 32); a5 += __shfl_xor(a5, 32);
                a6 += __shfl_xor(a6, 32); a7 += __shfl_xor(a7, 32);
                if (g == 0) {
                    uint4 o;
                    o.x = (unsigned int)f2bf(a0) | ((unsigned int)f2bf(a1) << 16);
                    o.y = (unsigned int)f2bf(a2) | ((unsigned int)f2bf(a3) << 16);
                    o.z = (unsigned int)f2bf(a4) | ((unsigned int)f2bf(a5) << 16);
                    o.w = (unsigned int)f2bf(a6) | ((unsigned int)f2bf(a7) << 16);
                    const int p = cl ^ (r & 7);  // swizzled chunk position
                    *(uint4*)(As + r * 128 + p * 8) = o;
                }
            }
        } else {
            // ---- contiguous hprev staging (root path) ----
            #pragma unroll
            for (int i = 0; i < 4; ++i) {
                const int r = i * 32 + (tid >> 4);
                const int p = tid & 15;
                const int gr = min(rb + r, nrows - 1);
                const int gc = p ^ (r & 7);
                const uint4 v = *(const uint4*)(hprev + (size_t)gr * 128 + gc * 8);
                *(uint4*)(As + r * 128 + p * 8) = v;
            }
        }
        #pragma unroll
        for (int i = 0; i < 4; ++i) {
            const int n = i * 32 + (tid >> 4);
            const int p = tid & 15;
            const int gc = s * 16 + (p ^ (n & 7));
            const uint4 v = *(const uint4*)(Wt + (size_t)n * 256 + gc * 8);
            *(uint4*)(Bs + n * 128 + p * 8) = v;
        }
        __syncthreads();
        #pragma unroll
        for (int kk = 0; kk < 4; ++kk) {
            short8 a[2], b[4];
            #pragma unroll
            for (int mf = 0; mf < 2; ++mf) {
                const int r = wm * 32 + mf * 16 + (lane & 15);
                const int p = (kk * 4 + (lane >> 4)) ^ (r & 7);
                a[mf] = *(const short8*)(As + r * 128 + p * 8);
            }
            #pragma unroll
            for (int nf = 0; nf < 4; ++nf) {
                const int n = wn * 64 + nf * 16 + (lane & 15);
                const int p = (kk * 4 + (lane >> 4)) ^ (n & 7);
                b[nf] = *(const short8*)(Bs + n * 128 + p * 8);
            }
            #pragma unroll
            for (int mf = 0; mf < 2; ++mf)
                #pragma unroll
                for (int nf = 0; nf < 4; ++nf)
                    acc[mf][nf] = __builtin_amdgcn_mfma_f32_16x16x32_bf16(
                        a[mf], b[nf], acc[mf][nf], 0, 0, 0);
        }
    }

    // epilogue: bias + wdeg*brel, gelu, store bf16, BN partials (fixed order, no atomics)
    int colv[4];
    float biasv[4], brelv[4];
    #pragma unroll
    for (int nf = 0; nf < 4; ++nf) {
        colv[nf] = wn * 64 + nf * 16 + (lane & 15);
        biasv[nf] = bias2[colv[nf]];
        brelv[nf] = brel[colv[nf]];
    }
    float ps[4] = {0.f, 0.f, 0.f, 0.f}, pq[4] = {0.f, 0.f, 0.f, 0.f};
    #pragma unroll
    for (int mf = 0; mf < 2; ++mf) {
        #pragma unroll
        for (int reg = 0; reg < 4; ++reg) {
            const int gm = rb + wm * 32 + mf * 16 + (lane >> 4) * 4 + reg;
            const bool valid = gm < nrows;
            const float wd = valid ? wdeg[gm] : 0.f;
            #pragma unroll
            for (int nf = 0; nf < 4; ++nf) {
                const float hv = gelu_f(acc[mf][nf][reg] + biasv[nf] + wd * brelv[nf]);
                if (valid) {
                    hnext[(size_t)gm * 128 + colv[nf]] = f2bf(hv);
                    ps[nf] += hv;
                    pq[nf] += hv * hv;
                }
            }
        }
    }
    #pragma unroll
    for (int nf = 0; nf < 4; ++nf) {
        ps[nf] += __shfl_xor(ps[nf], 16); ps[nf] += __shfl_xor(ps[nf], 32);
        pq[nf] += __shfl_xor(pq[nf], 16); pq[nf] += __shfl_xor(pq[nf], 32);
        if ((lane >> 4) == 0) {
            psb[wid * 64 + nf * 16 + (lane & 15)] = ps[nf];
            pqb[wid * 64 + nf * 16 + (lane & 15)] = pq[nf];
        }
    }
    __syncthreads();
    if (tid < 128) {
        const int wnh = tid >> 6;
        const int c64 = tid & 63;
        float s = 0.f, q = 0.f;
        #pragma unroll
        for (int w = 0; w < 4; ++w) {  // fixed order across waves
            s += psb[(w * 2 + wnh) * 64 + c64];
            q += pqb[(w * 2 + wnh) * 64 + c64];
        }
        bnpart[(size_t)tid * nblk + blockIdx.x] = s;
        bnpart[(size_t)(128 + tid) * nblk + blockIdx.x] = q;
    }
}

// parallel deterministic reduce: one block per column, coalesced reads, fixed-order tree
__global__ void k_bnred(const float* __restrict__ bnpart, int nblk, float* __restrict__ bn) {
    __shared__ float sh[256];
    const int tid = threadIdx.x;
    const int col = blockIdx.x;
    float s = 0.f;
    for (int i = tid; i < nblk; i += 256) s += bnpart[(size_t)col * nblk + i];
    sh[tid] = s;
    __syncthreads();
    #pragma unroll
    for (int off = 128; off >= 1; off >>= 1) {
        if (tid < off) sh[tid] += sh[tid + off];
        __syncthreads();
    }
    if (tid == 0) bn[col] = sh[0];
}

__global__ void k_bnfin(const float* __restrict__ bn, const float* __restrict__ g,
                        const float* __restrict__ b, float* __restrict__ sc) {
    int i = threadIdx.x;
    if (i < 128) {
        const float inv_n = 1.0f / (float)NN;
        const float mean = bn[i] * inv_n;
        const float var = bn[128 + i] * inv_n - mean * mean;
        const float s = g[i] * rsqrtf(var + BN_EPS);
        sc[i] = s;
        sc[128 + i] = b[i] - mean * s;
    }
}

// ---------------- MFMA edge MLP (deterministic row reduce) ----------------

__global__ __launch_bounds__(512, 4) void k_mlp2(
    const unsigned short* __restrict__ xf, const int* __restrict__ eli,
    const unsigned short* __restrict__ Wtm, const float* __restrict__ b1v,
    const float* __restrict__ w2, const float* __restrict__ b2,
    float* __restrict__ out, int nq) {
    __shared__ unsigned short As[128 * 128];
    __shared__ unsigned short Bs[128 * 128];
    __shared__ int sidx[256];
    __shared__ float rowred2[2][128];
    const int tid = threadIdx.x;
    const int qb = blockIdx.x * 128;
    if (tid < 256) {
        const int rr = tid & 127;
        const int q = qb + rr;
        sidx[tid] = (q < nq) ? eli[(tid >> 7) * NQ + q] : 0;
    }
    __syncthreads();

    const int lane = tid & 63;
    const int wid = tid >> 6;
    const int wm = wid >> 1, wn = wid & 1;

    f32x4 acc[2][4];
    #pragma unroll
    for (int mf = 0; mf < 2; ++mf)
        #pragma unroll
        for (int nf = 0; nf < 4; ++nf) acc[mf][nf] = (f32x4){0.f, 0.f, 0.f, 0.f};

    #pragma unroll
    for (int s = 0; s < 2; ++s) {
        if (s) __syncthreads();
        #pragma unroll
        for (int i = 0; i < 4; ++i) {
            const int r = i * 32 + (tid >> 4);
            const int p = tid & 15;
            const int node = sidx[s * 128 + r];
            const int gc = p ^ (r & 7);
            const uint4 v = *(const uint4*)(xf + (size_t)node * 128 + gc * 8);
            *(uint4*)(As + r * 128 + p * 8) = v;
        }
        #pragma unroll
        for (int i = 0; i < 4; ++i) {
            const int n = i * 32 + (tid >> 4);
            const int p = tid & 15;
            const int gc = s * 16 + (p ^ (n & 7));
            const uint4 v = *(const uint4*)(Wtm + (size_t)n * 256 + gc * 8);
            *(uint4*)(Bs + n * 128 + p * 8) = v;
        }
        __syncthreads();
        #pragma unroll
        for (int kk = 0; kk < 4; ++kk) {
            short8 a[2], b[4];
            #pragma unroll
            for (int mf = 0; mf < 2; ++mf) {
                const int r = wm * 32 + mf * 16 + (lane & 15);
                const int p = (kk * 4 + (lane >> 4)) ^ (r & 7);
                a[mf] = *(const short8*)(As + r * 128 + p * 8);
            }
            #pragma unroll
            for (int nf = 0; nf < 4; ++nf) {
                const int n = wn * 64 + nf * 16 + (lane & 15);
                const int p = (kk * 4 + (lane >> 4)) ^ (n & 7);
                b[nf] = *(const short8*)(Bs + n * 128 + p * 8);
            }
            #pragma unroll
            for (int mf = 0; mf < 2; ++mf)
                #pragma unroll
                for (int nf = 0; nf < 4; ++nf)
                    acc[mf][nf] = __builtin_amdgcn_mfma_f32_16x16x32_bf16(
                        a[mf], b[nf], acc[mf][nf], 0, 0, 0);
        }
    }

    int colv[4];
    float w2v[4], b1c[4];
    #pragma unroll
    for (int nf = 0; nf < 4; ++nf) {
        colv[nf] = wn * 64 + nf * 16 + (lane & 15);
        w2v[nf] = w2[colv[nf]];
        b1c[nf] = b1v[colv[nf]];
    }
    #pragma unroll
    for (int mf = 0; mf < 2; ++mf) {
        #pragma unroll
        for (int reg = 0; reg < 4; ++reg) {
            float part = 0.f;
            #pragma unroll
            for (int nf = 0; nf < 4; ++nf)
                part += gelu_f(acc[mf][nf][reg] + b1c[nf]) * w2v[nf];
            part += __shfl_xor(part, 1);
            part += __shfl_xor(part, 2);
            part += __shfl_xor(part, 4);
            part += __shfl_xor(part, 8);
            if ((lane & 15) == 0) {
                const int lr = wm * 32 + mf * 16 + (lane >> 4) * 4 + reg;
                rowred2[wn][lr] = part;  // unique writer per (wn, lr)
            }
        }
    }
    __syncthreads();
    if (tid < 128) {
        const int q = qb + tid;
        if (q < nq)
            out[q] = 1.0f / (1.0f + expf(-(rowred2[0][tid] + rowred2[1][tid] + b2[0])));
    }
}

// ---------------- launcher ----------------

extern "C" void kernel_launch(void* const* d_in, const int* in_sizes, int n_in,
                              void* d_out, int out_size, void* d_ws, size_t ws_size,
                              hipStream_t stream) {
    const float* x_in = (const float*)d_in[0];
    const int* ei = (const int*)d_in[1];
    const float* ea = (const float*)d_in[2];
    const int* eli = (const int*)d_in[3];
    const float* rel_w = (const float*)d_in[4];
    const float* rel_b = (const float*)d_in[5];
    const float* root_w = (const float*)d_in[6];
    const float* bn_g = (const float*)d_in[7];
    const float* bn_b = (const float*)d_in[8];
    const float* w1 = (const float*)d_in[9];
    const float* b1 = (const float*)d_in[10];
    const float* w2 = (const float*)d_in[11];
    const float* b2 = (const float*)d_in[12];
    float* out = (float*)d_out;

    char* ws = (char*)d_ws;
    size_t off = 0;
    auto alloc = [&](size_t bytes) -> void* {
        void* p = ws + off;
        off = (off + bytes + 255) & ~(size_t)255;
        return p;
    };
    const int nblk_gemm = (NN + 127) / 128;  // 782
    unsigned short* hb0 = (unsigned short*)alloc(2ull * NN * HID);
    unsigned short* hb1 = (unsigned short*)alloc(2ull * NN * HID);
    int* eord = (int*)alloc(sizeof(int) * EE);
    int* csrc = (int*)alloc(sizeof(int) * EE);
    float* cea = (float*)alloc(sizeof(float) * EE);
    int* rp = (int*)alloc(sizeof(int) * (NN + 1));
    int* cnt = (int*)alloc(sizeof(int) * NN);
    int* bsum = (int*)alloc(sizeof(int) * 256);
    float* wdeg = (float*)alloc(sizeof(float) * NN);
    float* bnpart = (float*)alloc(sizeof(float) * 256 * (size_t)nblk_gemm);
    float* bn = (float*)alloc(sizeof(float) * 256);
    float* bnsc = (float*)alloc(sizeof(float) * 256);
    unsigned short* Wt = (unsigned short*)alloc(2ull * 128 * 256);
    unsigned short* Wtm = (unsigned short*)alloc(2ull * 128 * 256);
    float* bias2 = (float*)alloc(sizeof(float) * 128);
    float* brel = (float*)alloc(sizeof(float) * 128);
    float* b1v = (float*)alloc(sizeof(float) * 128);
    (void)ws_size;

    const int nb_scan = (NN + 1023) / 1024;

    // input -> bf16
    k_cvt<<<(NN * 64 + 255) / 256, 256, 0, stream>>>(x_in, (unsigned int*)hb0, NN * 64);

    // CSR build (deterministic final arrays)
    k_zero_int<<<(NN + 255) / 256, 256, 0, stream>>>(cnt, NN);
    k_hist<<<(EE + 255) / 256, 256, 0, stream>>>(ei, cnt);
    k_scan1<<<nb_scan, 256, 0, stream>>>(cnt, rp, bsum, NN);
    k_scan2<<<1, 256, 0, stream>>>(bsum, nb_scan);
    k_scan3<<<(NN + 255) / 256, 256, 0, stream>>>(rp, bsum, cnt, NN);
    k_fill<<<(EE + 255) / 256, 256, 0, stream>>>(ei, rp, cnt, eord);
    k_sortfill<<<(NN + 255) / 256, 256, 0, stream>>>(ei, ea, rp, eord, csrc, cea, wdeg);
    k_bninit<<<1, 256, 0, stream>>>(bnsc);

    unsigned short* hcur = hb0;
    unsigned short* bufs[2] = {hb1, hb0};
    for (int l = 0; l < NL; ++l) {
        unsigned short* hnext = bufs[l & 1];
        k_wprep<<<128, 256, 0, stream>>>(rel_w + (size_t)l * HID * HID,
                                         root_w + (size_t)l * HID * HID,
                                         rel_b + (size_t)l * HID, bnsc, Wt, bias2, brel);
        k_gemm2<<<nblk_gemm, 512, 0, stream>>>(hcur, csrc, cea, rp, Wt, bias2, brel, wdeg,
                                               hnext, bnpart, NN, nblk_gemm);
        k_bnred<<<256, 256, 0, stream>>>(bnpart, nblk_gemm, bn);
        k_bnfin<<<1, 128, 0, stream>>>(bn, bn_g + (size_t)l * HID, bn_b + (size_t)l * HID, bnsc);
        hcur = hnext;
    }

    k_mlpprep<<<128, 256, 0, stream>>>(w1, b1, bnsc, Wtm, b1v);
    k_mlp2<<<(NQ + 127) / 128, 512, 0, stream>>>(hcur, eli, Wtm, b1v, w2, b2, out, NQ);
}

// Round 9
// 457.672 us; speedup vs baseline: 3.1383x; 1.0195x over previous
//
#include <hip/hip_runtime.h>

#define NN 100000
#define EE 600000
#define NQ 200000
#define HID 128
#define NL 4
#define BN_EPS 1e-5f
#define ECAP 1280  // LDS edge-staging capacity (10 KB); fallback to global if exceeded

typedef __attribute__((ext_vector_type(8))) short short8;
typedef __attribute__((ext_vector_type(4))) float f32x4;

__device__ __forceinline__ float gelu_f(float v) {
    return 0.5f * v * (1.0f + erff(v * 0.70710678118654752f));
}
__device__ __forceinline__ unsigned short f2bf(float f) {
    unsigned int x = __float_as_uint(f);
    unsigned int r = (x + 0x7FFFu + ((x >> 16) & 1u)) >> 16;
    return (unsigned short)r;
}
__device__ __forceinline__ float bf2f(unsigned short u) {
    return __uint_as_float(((unsigned int)u) << 16);
}

// ---------------- small utility kernels ----------------

__global__ void k_zero_int(int* __restrict__ p, int n) {
    int i = blockIdx.x * blockDim.x + threadIdx.x;
    if (i < n) p[i] = 0;
}

__global__ void k_cvt(const float* __restrict__ x, unsigned int* __restrict__ o, int n2) {
    int i = blockIdx.x * blockDim.x + threadIdx.x;
    if (i < n2) {
        float2 v = ((const float2*)x)[i];
        o[i] = (unsigned int)f2bf(v.x) | ((unsigned int)f2bf(v.y) << 16);
    }
}

__global__ void k_bninit(float* __restrict__ sc) {
    int i = threadIdx.x;
    sc[i] = (i < 128) ? 1.0f : 0.0f;
}

// ---------------- CSR build (deterministic) ----------------

__global__ void k_hist(const int* __restrict__ ei, int* __restrict__ cnt) {
    int e = blockIdx.x * blockDim.x + threadIdx.x;
    if (e < EE) atomicAdd(&cnt[ei[EE + e]], 1);  // int atomics: deterministic result
}

__global__ void k_scan1(const int* __restrict__ cnt, int* __restrict__ rp,
                        int* __restrict__ bsum, int n) {
    __shared__ int sh[256];
    const int tid = threadIdx.x;
    const int base = blockIdx.x * 1024;
    int v[4];
    int s = 0;
    #pragma unroll
    for (int j = 0; j < 4; ++j) {
        int idx = base + tid * 4 + j;
        v[j] = (idx < n) ? cnt[idx] : 0;
        s += v[j];
    }
    sh[tid] = s;
    __syncthreads();
    for (int off = 1; off < 256; off <<= 1) {
        int t = (tid >= off) ? sh[tid - off] : 0;
        __syncthreads();
        sh[tid] += t;
        __syncthreads();
    }
    int run = sh[tid] - s;
    #pragma unroll
    for (int j = 0; j < 4; ++j) {
        int idx = base + tid * 4 + j;
        if (idx < n) rp[idx] = run;
        run += v[j];
    }
    if (tid == 255) bsum[blockIdx.x] = sh[255];
}

__global__ void k_scan2(int* __restrict__ bsum, int nb) {
    __shared__ int sh[256];
    const int tid = threadIdx.x;
    int v = (tid < nb) ? bsum[tid] : 0;
    sh[tid] = v;
    __syncthreads();
    for (int off = 1; off < 256; off <<= 1) {
        int t = (tid >= off) ? sh[tid - off] : 0;
        __syncthreads();
        sh[tid] += t;
        __syncthreads();
    }
    if (tid < nb) bsum[tid] = sh[tid] - v;
}

__global__ void k_scan3(int* __restrict__ rp, const int* __restrict__ bsum,
                        int* __restrict__ cnt, int n) {
    int i = blockIdx.x * blockDim.x + threadIdx.x;
    if (i < n) {
        rp[i] += bsum[i >> 10];
        cnt[i] = 0;
    }
    if (i == 0) rp[n] = EE;
}

// slot assignment is atomic-order-dependent; only edge ids are stored here
__global__ void k_fill(const int* __restrict__ ei, const int* __restrict__ rp,
                       int* __restrict__ cur, int* __restrict__ eord) {
    int e = blockIdx.x * blockDim.x + threadIdx.x;
    if (e < EE) {
        int d = ei[EE + e];
        int p = rp[d] + atomicAdd(&cur[d], 1);
        eord[p] = e;
    }
}

// canonicalize: sort each segment by edge id, then materialize csrc/cea/wdeg.
__global__ void k_sortfill(const int* __restrict__ ei, const float* __restrict__ ea,
                           const int* __restrict__ rp, int* __restrict__ eord,
                           int* __restrict__ csrc, float* __restrict__ cea,
                           float* __restrict__ wdeg) {
    int n = blockIdx.x * blockDim.x + threadIdx.x;
    if (n >= NN) return;
    const int s0 = rp[n], s1 = rp[n + 1];
    for (int i = s0 + 1; i < s1; ++i) {
        int key = eord[i];
        int j = i - 1;
        while (j >= s0 && eord[j] > key) { eord[j + 1] = eord[j]; --j; }
        eord[j + 1] = key;
    }
    float s = 0.f;
    for (int i = s0; i < s1; ++i) {
        const int e = eord[i];
        csrc[i] = ei[e];
        const float w = ea[e];
        cea[i] = w;
        s += w;
    }
    wdeg[n] = s;
}

// ---------------- weight prep (parallel, BN affine folded, fragment layout) ----------------
// Wtf fragment-linear layout: for fragment (kc = k>>5 in [0,8), nb = n>>4 in [0,8)):
//   Wtf[(kc*8+nb)*512 + lane*8 + e] with lane = ((k>>3)&3)*16 + (n&15), e = k&7
// holds sc[k&127] * (k<128 ? relw[k][n] : rootw[k-128][n]).
// A wave's B-fragment load is then one coalesced 1KB short8 read (L2-resident).

__global__ void k_wprep(const float* __restrict__ relw, const float* __restrict__ rootw,
                        const float* __restrict__ relb, const float* __restrict__ sc,
                        unsigned short* __restrict__ Wtf, float* __restrict__ bias2,
                        float* __restrict__ brel) {
    __shared__ float shb[256];
    const int n = blockIdx.x;
    const int k = threadIdx.x;
    const float s = sc[k & 127];
    const float w = (k < 128) ? relw[(size_t)k * HID + n] : rootw[(size_t)(k - 128) * HID + n];
    const int nb = n >> 4, l15 = n & 15;
    const int kc = k >> 5, kg = (k >> 3) & 3, e = k & 7;
    Wtf[((size_t)(kc * 8 + nb) * 512) + (kg * 16 + l15) * 8 + e] = f2bf(s * w);
    shb[k] = sc[128 + (k & 127)] * w;
    __syncthreads();
    #pragma unroll
    for (int off = 64; off >= 1; off >>= 1) {
        if (k < off) shb[k] += shb[k + off];
        else if (k >= 128 && k < 128 + off) shb[k] += shb[k + off];
        __syncthreads();
    }
    if (k == 0) brel[n] = shb[0];
    if (k == 128) bias2[n] = relb[n] + shb[128];
}

__global__ void k_mlpprep(const float* __restrict__ w1, const float* __restrict__ b1,
                          const float* __restrict__ sc, unsigned short* __restrict__ Wtm,
                          float* __restrict__ b1v) {
    __shared__ float shb[256];
    const int n = blockIdx.x;
    const int k = threadIdx.x;
    const float w = w1[(size_t)k * HID + n];
    Wtm[(size_t)n * 256 + k] = f2bf(sc[k & 127] * w);
    shb[k] = sc[128 + (k & 127)] * w;
    __syncthreads();
    #pragma unroll
    for (int off = 128; off >= 1; off >>= 1) {
        if (k < off) shb[k] += shb[k + off];
        __syncthreads();
    }
    if (k == 0) b1v[n] = b1[n] + shb[0];
}

// ---------------- fused gather + MFMA conv GEMM ----------------
// No Bs staging: B-fragments read straight from L2-resident Wtf (same 64KB for
// all blocks). LDS ~48KB -> 3 blocks/CU. Gather: LDS-staged edge list + 2-wide
// edge ILP. Fixed-order combine = deterministic.

__global__ __launch_bounds__(512, 6) void k_gemm2(
    const unsigned short* __restrict__ hprev, const int* __restrict__ csrc,
    const float* __restrict__ cea, const int* __restrict__ rp,
    const unsigned short* __restrict__ Wtf, const float* __restrict__ bias2,
    const float* __restrict__ brel, const float* __restrict__ wdeg,
    unsigned short* __restrict__ hnext, float* __restrict__ bnpart,
    int nrows, int nblk) {
    __shared__ unsigned short As[128 * 128];
    __shared__ float psb[8 * 64];
    __shared__ float pqb[8 * 64];
    __shared__ int eidx[ECAP];
    __shared__ float ew[ECAP];
    __shared__ int rps[132];
    const int tid = threadIdx.x;
    const int rb = blockIdx.x * 128;

    const int lane = tid & 63;
    const int wid = tid >> 6;
    const int wm = wid >> 1, wn = wid & 1;

    // stage row bounds + edge data
    if (tid < 129) {
        int nn = rb + tid;
        rps[tid] = rp[nn < nrows ? nn : nrows];
    }
    __syncthreads();
    const int e0 = rps[0];
    const int ne = rps[128] - e0;
    const bool useLds = (ne <= ECAP);
    if (useLds) {
        for (int i = tid; i < ne; i += 512) {
            eidx[i] = csrc[e0 + i];
            ew[i] = cea[e0 + i];
        }
    }

    f32x4 acc[2][4];
    #pragma unroll
    for (int mf = 0; mf < 2; ++mf)
        #pragma unroll
        for (int nf = 0; nf < 4; ++nf) acc[mf][nf] = (f32x4){0.f, 0.f, 0.f, 0.f};

    #pragma unroll
    for (int s = 0; s < 2; ++s) {
        __syncthreads();
        if (s == 0) {
            // ---- gather-staging: wave w owns rows w*16 .. w*16+15 ----
            const int g = lane >> 4;        // edge sub-group 0..3
            const int cl = lane & 15;       // 16B chunk within the row
            for (int rr = 0; rr < 16; ++rr) {
                const int r = wid * 16 + rr;
                const int s0 = rps[r] - e0, s1 = rps[r + 1] - e0;
                float a0 = 0.f, a1 = 0.f, a2 = 0.f, a3 = 0.f,
                      a4 = 0.f, a5 = 0.f, a6 = 0.f, a7 = 0.f;
                for (int i = s0 + g; i < s1; i += 8) {
                    const int i2 = i + 4;
                    const bool has2 = i2 < s1;
                    int src1, src2;
                    float w1, w2;
                    if (useLds) {
                        src1 = eidx[i]; w1 = ew[i];
                        src2 = has2 ? eidx[i2] : src1;
                        w2 = has2 ? ew[i2] : 0.f;
                    } else {
                        src1 = csrc[e0 + i]; w1 = cea[e0 + i];
                        src2 = has2 ? csrc[e0 + i2] : src1;
                        w2 = has2 ? cea[e0 + i2] : 0.f;
                    }
                    const uint4 va = *(const uint4*)(hprev + (size_t)src1 * HID + cl * 8);
                    const uint4 vb = *(const uint4*)(hprev + (size_t)src2 * HID + cl * 8);
                    a0 += bf2f((unsigned short)(va.x)) * w1;
                    a1 += bf2f((unsigned short)(va.x >> 16)) * w1;
                    a2 += bf2f((unsigned short)(va.y)) * w1;
                    a3 += bf2f((unsigned short)(va.y >> 16)) * w1;
                    a4 += bf2f((unsigned short)(va.z)) * w1;
                    a5 += bf2f((unsigned short)(va.z >> 16)) * w1;
                    a6 += bf2f((unsigned short)(va.w)) * w1;
                    a7 += bf2f((unsigned short)(va.w >> 16)) * w1;
                    a0 += bf2f((unsigned short)(vb.x)) * w2;
                    a1 += bf2f((unsigned short)(vb.x >> 16)) * w2;
                    a2 += bf2f((unsigned short)(vb.y)) * w2;
                    a3 += bf2f((unsigned short)(vb.y >> 16)) * w2;
                    a4 += bf2f((unsigned short)(vb.z)) * w2;
                    a5 += bf2f((unsigned short)(vb.z >> 16)) * w2;
                    a6 += bf2f((unsigned short)(vb.w)) * w2;
                    a7 += bf2f((unsigned short)(vb.w >> 16)) * w2;
                }
                // fixed-order cross-group combine — deterministic tree
                a0 += __shfl_xor(a0, 16); a1 += __shfl_xor(a1, 16);
                a2 += __shfl_xor(a2, 16); a3 += __shfl_xor(a3, 16);
                a4 += __shfl_xor(a4, 16); a5 += __shfl_xor(a5, 16);
                a6 += __shfl_xor(a6, 16); a7 += __shfl_xor(a7, 16);
                a0 += __shfl_xor(a0, 32); a1 += __shfl_xor(a1, 32);
                a2 += __shfl_xor(a2, 32); a3 += __shfl_xor(a3, 32);
                a4 += __shfl_xor(a4, 32); a5 += __shfl_xor(a5, 32);
                a6 += __shfl_xor(a6, 32); a7 += __shfl_xor(a7, 32);
                if (g == 0) {
                    uint4 o;
                    o.x = (unsigned int)f2bf(a0) | ((unsigned int)f2bf(a1) << 16);
                    o.y = (unsigned int)f2bf(a2) | ((unsigned int)f2bf(a3) << 16);
                    o.z = (unsigned int)f2bf(a4) | ((unsigned int)f2bf(a5) << 16);
                    o.w = (unsigned int)f2bf(a6) | ((unsigned int)f2bf(a7) << 16);
                    const int p = cl ^ (r & 7);  // swizzled chunk position
                    *(uint4*)(As + r * 128 + p * 8) = o;
                }
            }
        } else {
            // ---- contiguous hprev staging (root path) ----
            #pragma unroll
            for (int i = 0; i < 4; ++i) {
                const int r = i * 32 + (tid >> 4);
                const int p = tid & 15;
                const int gr = min(rb + r, nrows - 1);
                const int gc = p ^ (r & 7);
                const uint4 v = *(const uint4*)(hprev + (size_t)gr * 128 + gc * 8);
                *(uint4*)(As + r * 128 + p * 8) = v;
            }
        }
        __syncthreads();
        #pragma unroll
        for (int kk = 0; kk < 4; ++kk) {
            short8 a[2], b[4];
            #pragma unroll
            for (int mf = 0; mf < 2; ++mf) {
                const int r = wm * 32 + mf * 16 + (lane & 15);
                const int p = (kk * 4 + (lane >> 4)) ^ (r & 7);
                a[mf] = *(const short8*)(As + r * 128 + p * 8);
            }
            #pragma unroll
            for (int nf = 0; nf < 4; ++nf) {
                // fragment-linear, coalesced, L2-resident
                b[nf] = *(const short8*)(Wtf + ((size_t)((s * 4 + kk) * 8 + wn * 4 + nf) * 512)
                                               + lane * 8);
            }
            #pragma unroll
            for (int mf = 0; mf < 2; ++mf)
                #pragma unroll
                for (int nf = 0; nf < 4; ++nf)
                    acc[mf][nf] = __builtin_amdgcn_mfma_f32_16x16x32_bf16(
                        a[mf], b[nf], acc[mf][nf], 0, 0, 0);
        }
    }

    // epilogue: bias + wdeg*brel, gelu, store bf16, BN partials (fixed order, no atomics)
    int colv[4];
    float biasv[4], brelv[4];
    #pragma unroll
    for (int nf = 0; nf < 4; ++nf) {
        colv[nf] = wn * 64 + nf * 16 + (lane & 15);
        biasv[nf] = bias2[colv[nf]];
        brelv[nf] = brel[colv[nf]];
    }
    float ps[4] = {0.f, 0.f, 0.f, 0.f}, pq[4] = {0.f, 0.f, 0.f, 0.f};
    #pragma unroll
    for (int mf = 0; mf < 2; ++mf) {
        #pragma unroll
        for (int reg = 0; reg < 4; ++reg) {
            const int gm = rb + wm * 32 + mf * 16 + (lane >> 4) * 4 + reg;
            const bool valid = gm < nrows;
            const float wd = valid ? wdeg[gm] : 0.f;
            #pragma unroll
            for (int nf = 0; nf < 4; ++nf) {
                const float hv = gelu_f(acc[mf][nf][reg] + biasv[nf] + wd * brelv[nf]);
                if (valid) {
                    hnext[(size_t)gm * 128 + colv[nf]] = f2bf(hv);
                    ps[nf] += hv;
                    pq[nf] += hv * hv;
                }
            }
        }
    }
    #pragma unroll
    for (int nf = 0; nf < 4; ++nf) {
        ps[nf] += __shfl_xor(ps[nf], 16); ps[nf] += __shfl_xor(ps[nf], 32);
        pq[nf] += __shfl_xor(pq[nf], 16); pq[nf] += __shfl_xor(pq[nf], 32);
        if ((lane >> 4) == 0) {
            psb[wid * 64 + nf * 16 + (lane & 15)] = ps[nf];
            pqb[wid * 64 + nf * 16 + (lane & 15)] = pq[nf];
        }
    }
    __syncthreads();
    if (tid < 128) {
        const int wnh = tid >> 6;
        const int c64 = tid & 63;
        float s = 0.f, q = 0.f;
        #pragma unroll
        for (int w = 0; w < 4; ++w) {  // fixed order across waves
            s += psb[(w * 2 + wnh) * 64 + c64];
            q += pqb[(w * 2 + wnh) * 64 + c64];
        }
        bnpart[(size_t)tid * nblk + blockIdx.x] = s;
        bnpart[(size_t)(128 + tid) * nblk + blockIdx.x] = q;
    }
}

// parallel deterministic reduce: one block per column, coalesced reads, fixed-order tree
__global__ void k_bnred(const float* __restrict__ bnpart, int nblk, float* __restrict__ bn) {
    __shared__ float sh[256];
    const int tid = threadIdx.x;
    const int col = blockIdx.x;
    float s = 0.f;
    for (int i = tid; i < nblk; i += 256) s += bnpart[(size_t)col * nblk + i];
    sh[tid] = s;
    __syncthreads();
    #pragma unroll
    for (int off = 128; off >= 1; off >>= 1) {
        if (tid < off) sh[tid] += sh[tid + off];
        __syncthreads();
    }
    if (tid == 0) bn[col] = sh[0];
}

__global__ void k_bnfin(const float* __restrict__ bn, const float* __restrict__ g,
                        const float* __restrict__ b, float* __restrict__ sc) {
    int i = threadIdx.x;
    if (i < 128) {
        const float inv_n = 1.0f / (float)NN;
        const float mean = bn[i] * inv_n;
        const float var = bn[128 + i] * inv_n - mean * mean;
        const float s = g[i] * rsqrtf(var + BN_EPS);
        sc[i] = s;
        sc[128 + i] = b[i] - mean * s;
    }
}

// ---------------- MFMA edge MLP (deterministic row reduce) ----------------

__global__ __launch_bounds__(512, 4) void k_mlp2(
    const unsigned short* __restrict__ xf, const int* __restrict__ eli,
    const unsigned short* __restrict__ Wtm, const float* __restrict__ b1v,
    const float* __restrict__ w2, const float* __restrict__ b2,
    float* __restrict__ out, int nq) {
    __shared__ unsigned short As[128 * 128];
    __shared__ unsigned short Bs[128 * 128];
    __shared__ int sidx[256];
    __shared__ float rowred2[2][128];
    const int tid = threadIdx.x;
    const int qb = blockIdx.x * 128;
    if (tid < 256) {
        const int rr = tid & 127;
        const int q = qb + rr;
        sidx[tid] = (q < nq) ? eli[(tid >> 7) * NQ + q] : 0;
    }
    __syncthreads();

    const int lane = tid & 63;
    const int wid = tid >> 6;
    const int wm = wid >> 1, wn = wid & 1;

    f32x4 acc[2][4];
    #pragma unroll
    for (int mf = 0; mf < 2; ++mf)
        #pragma unroll
        for (int nf = 0; nf < 4; ++nf) acc[mf][nf] = (f32x4){0.f, 0.f, 0.f, 0.f};

    #pragma unroll
    for (int s = 0; s < 2; ++s) {
        if (s) __syncthreads();
        #pragma unroll
        for (int i = 0; i < 4; ++i) {
            const int r = i * 32 + (tid >> 4);
            const int p = tid & 15;
            const int node = sidx[s * 128 + r];
            const int gc = p ^ (r & 7);
            const uint4 v = *(const uint4*)(xf + (size_t)node * 128 + gc * 8);
            *(uint4*)(As + r * 128 + p * 8) = v;
        }
        #pragma unroll
        for (int i = 0; i < 4; ++i) {
            const int n = i * 32 + (tid >> 4);
            const int p = tid & 15;
            const int gc = s * 16 + (p ^ (n & 7));
            const uint4 v = *(const uint4*)(Wtm + (size_t)n * 256 + gc * 8);
            *(uint4*)(Bs + n * 128 + p * 8) = v;
        }
        __syncthreads();
        #pragma unroll
        for (int kk = 0; kk < 4; ++kk) {
            short8 a[2], b[4];
            #pragma unroll
            for (int mf = 0; mf < 2; ++mf) {
                const int r = wm * 32 + mf * 16 + (lane & 15);
                const int p = (kk * 4 + (lane >> 4)) ^ (r & 7);
                a[mf] = *(const short8*)(As + r * 128 + p * 8);
            }
            #pragma unroll
            for (int nf = 0; nf < 4; ++nf) {
                const int n = wn * 64 + nf * 16 + (lane & 15);
                const int p = (kk * 4 + (lane >> 4)) ^ (n & 7);
                b[nf] = *(const short8*)(Bs + n * 128 + p * 8);
            }
            #pragma unroll
            for (int mf = 0; mf < 2; ++mf)
                #pragma unroll
                for (int nf = 0; nf < 4; ++nf)
                    acc[mf][nf] = __builtin_amdgcn_mfma_f32_16x16x32_bf16(
                        a[mf], b[nf], acc[mf][nf], 0, 0, 0);
        }
    }

    int colv[4];
    float w2v[4], b1c[4];
    #pragma unroll
    for (int nf = 0; nf < 4; ++nf) {
        colv[nf] = wn * 64 + nf * 16 + (lane & 15);
        w2v[nf] = w2[colv[nf]];
        b1c[nf] = b1v[colv[nf]];
    }
    #pragma unroll
    for (int mf = 0; mf < 2; ++mf) {
        #pragma unroll
        for (int reg = 0; reg < 4; ++reg) {
            float part = 0.f;
            #pragma unroll
            for (int nf = 0; nf < 4; ++nf)
                part += gelu_f(acc[mf][nf][reg] + b1c[nf]) * w2v[nf];
            part += __shfl_xor(part, 1);
            part += __shfl_xor(part, 2);
            part += __shfl_xor(part, 4);
            part += __shfl_xor(part, 8);
            if ((lane & 15) == 0) {
                const int lr = wm * 32 + mf * 16 + (lane >> 4) * 4 + reg;
                rowred2[wn][lr] = part;  // unique writer per (wn, lr)
            }
        }
    }
    __syncthreads();
    if (tid < 128) {
        const int q = qb + tid;
        if (q < nq)
            out[q] = 1.0f / (1.0f + expf(-(rowred2[0][tid] + rowred2[1][tid] + b2[0])));
    }
}

// ---------------- launcher ----------------

extern "C" void kernel_launch(void* const* d_in, const int* in_sizes, int n_in,
                              void* d_out, int out_size, void* d_ws, size_t ws_size,
                              hipStream_t stream) {
    const float* x_in = (const float*)d_in[0];
    const int* ei = (const int*)d_in[1];
    const float* ea = (const float*)d_in[2];
    const int* eli = (const int*)d_in[3];
    const float* rel_w = (const float*)d_in[4];
    const float* rel_b = (const float*)d_in[5];
    const float* root_w = (const float*)d_in[6];
    const float* bn_g = (const float*)d_in[7];
    const float* bn_b = (const float*)d_in[8];
    const float* w1 = (const float*)d_in[9];
    const float* b1 = (const float*)d_in[10];
    const float* w2 = (const float*)d_in[11];
    const float* b2 = (const float*)d_in[12];
    float* out = (float*)d_out;

    char* ws = (char*)d_ws;
    size_t off = 0;
    auto alloc = [&](size_t bytes) -> void* {
        void* p = ws + off;
        off = (off + bytes + 255) & ~(size_t)255;
        return p;
    };
    const int nblk_gemm = (NN + 127) / 128;  // 782
    unsigned short* hb0 = (unsigned short*)alloc(2ull * NN * HID);
    unsigned short* hb1 = (unsigned short*)alloc(2ull * NN * HID);
    int* eord = (int*)alloc(sizeof(int) * EE);
    int* csrc = (int*)alloc(sizeof(int) * EE);
    float* cea = (float*)alloc(sizeof(float) * EE);
    int* rp = (int*)alloc(sizeof(int) * (NN + 1));
    int* cnt = (int*)alloc(sizeof(int) * NN);
    int* bsum = (int*)alloc(sizeof(int) * 256);
    float* wdeg = (float*)alloc(sizeof(float) * NN);
    float* bnpart = (float*)alloc(sizeof(float) * 256 * (size_t)nblk_gemm);
    float* bn = (float*)alloc(sizeof(float) * 256);
    float* bnsc = (float*)alloc(sizeof(float) * 256);
    unsigned short* Wtf = (unsigned short*)alloc(2ull * 128 * 256);
    unsigned short* Wtm = (unsigned short*)alloc(2ull * 128 * 256);
    float* bias2 = (float*)alloc(sizeof(float) * 128);
    float* brel = (float*)alloc(sizeof(float) * 128);
    float* b1v = (float*)alloc(sizeof(float) * 128);
    (void)ws_size;

    const int nb_scan = (NN + 1023) / 1024;

    // input -> bf16
    k_cvt<<<(NN * 64 + 255) / 256, 256, 0, stream>>>(x_in, (unsigned int*)hb0, NN * 64);

    // CSR build (deterministic final arrays)
    k_zero_int<<<(NN + 255) / 256, 256, 0, stream>>>(cnt, NN);
    k_hist<<<(EE + 255) / 256, 256, 0, stream>>>(ei, cnt);
    k_scan1<<<nb_scan, 256, 0, stream>>>(cnt, rp, bsum, NN);
    k_scan2<<<1, 256, 0, stream>>>(bsum, nb_scan);
    k_scan3<<<(NN + 255) / 256, 256, 0, stream>>>(rp, bsum, cnt, NN);
    k_fill<<<(EE + 255) / 256, 256, 0, stream>>>(ei, rp, cnt, eord);
    k_sortfill<<<(NN + 255) / 256, 256, 0, stream>>>(ei, ea, rp, eord, csrc, cea, wdeg);
    k_bninit<<<1, 256, 0, stream>>>(bnsc);

    unsigned short* hcur = hb0;
    unsigned short* bufs[2] = {hb1, hb0};
    for (int l = 0; l < NL; ++l) {
        unsigned short* hnext = bufs[l & 1];
        k_wprep<<<128, 256, 0, stream>>>(rel_w + (size_t)l * HID * HID,
                                         root_w + (size_t)l * HID * HID,
                                         rel_b + (size_t)l * HID, bnsc, Wtf, bias2, brel);
        k_gemm2<<<nblk_gemm, 512, 0, stream>>>(hcur, csrc, cea, rp, Wtf, bias2, brel, wdeg,
                                               hnext, bnpart, NN, nblk_gemm);
        k_bnred<<<256, 256, 0, stream>>>(bnpart, nblk_gemm, bn);
        k_bnfin<<<1, 128, 0, stream>>>(bn, bn_g + (size_t)l * HID, bn_b + (size_t)l * HID, bnsc);
        hcur = hnext;
    }

    k_mlpprep<<<128, 256, 0, stream>>>(w1, b1, bnsc, Wtm, b1v);
    k_mlp2<<<(NQ + 127) / 128, 512, 0, stream>>>(hcur, eli, Wtm, b1v, w2, b2, out, NQ);
}